// Round 5
// baseline (447.056 us; speedup 1.0000x reference)
//
#include <hip/hip_runtime.h>

#define D 128
#define NLVL 17          // parent levels 0..16
#define TS 128           // rows per big GEMM tile
#define LVLPAD 1024      // per-level perm slack for group padding
#define LDSTR 136        // LDS row stride in bf16 elems (272B: conflict-free b128)
#define NB 32            // persistent top-levels grid (must all be co-resident)
#define LEAF_BLKS 1032   // ceil((131072 + 8*127)/128)

typedef float  floatx4 __attribute__((ext_vector_type(4)));
typedef short  shortx8 __attribute__((ext_vector_type(8)));

__device__ __forceinline__ unsigned short f2bf(float f) {   // RNE fp32->bf16
    unsigned u = __float_as_uint(f);
    u += 0x7FFFu + ((u >> 16) & 1u);
    return (unsigned short)(u >> 16);
}
__device__ __forceinline__ float bf2f(unsigned short h) {
    return __uint_as_float(((unsigned)h) << 16);
}
__device__ __forceinline__ int lvl_base_dev(int l) { return ((2 << l) - 2) + LVLPAD * l; }

// ============ sort step 1: per-(level,edge) counts ============
__global__ __launch_bounds__(256) void count_kernel(
    const int* __restrict__ edges, int* __restrict__ gcnt, int Nn)
{
    __shared__ int lc[NLVL * 8];
    const int t = threadIdx.x;
    for (int i = t; i < NLVL * 8; i += 256) lc[i] = 0;
    __syncthreads();
    for (int c = 1 + blockIdx.x * 256 + t; c < Nn; c += gridDim.x * 256) {
        const int e = edges[c];
        const int p = (c - 1) >> 1;
        const int l = 31 - __clz(p + 1);
        atomicAdd(&lc[l * 8 + e], 1);
    }
    __syncthreads();
    for (int i = t; i < NLVL * 8; i += 256) if (lc[i]) atomicAdd(&gcnt[i], lc[i]);
}

// ============ sort step 2: padded prefix (+ sv = data_W @ score_W, s0 = data_b . score_W) ============
// levels >= 11 pad groups to 128 (big tile kernel); levels <= 10 pad to 16 (persistent kernel)
__global__ __launch_bounds__(256) void prefix_sv_kernel(
    const int* __restrict__ gcnt, int* __restrict__ gstart,
    const float* __restrict__ dW, const float* __restrict__ db,
    const float* __restrict__ sWs, float* __restrict__ sv, float* __restrict__ s0)
{
    __shared__ float red[256];
    const int t = threadIdx.x;
    if (t < D) {
        float acc = 0.f;
        for (int j = 0; j < D; j++) acc += dW[t * D + j] * sWs[j];
        sv[t] = acc;
    }
    red[t] = (t < D) ? db[t] * sWs[t] : 0.f;
    __syncthreads();
    for (int s = 128; s > 0; s >>= 1) { if (t < s) red[t] += red[t + s]; __syncthreads(); }
    if (t == 0) {
        *s0 = red[0];
        for (int l = 0; l < NLVL; l++) {
            const int pad = (l >= 11) ? (TS - 1) : 15;
            int acc = 0;
            for (int e = 0; e < 8; e++) {
                gstart[l * 9 + e] = acc;
                acc = (acc + gcnt[l * 8 + e] + pad) & ~pad;
            }
            gstart[l * 9 + 8] = acc;
        }
    }
}

// ============ sort step 3: placement ============
#define CHUNK 2048
__global__ __launch_bounds__(256) void place_kernel(
    const int* __restrict__ edges, const int* __restrict__ gstart,
    int* __restrict__ ctr, int* __restrict__ perm, int Nn)
{
    __shared__ unsigned char key_s[CHUNK];
    __shared__ int lcnt[NLVL * 8], lbase[NLVL * 8];
    __shared__ int gs_s[NLVL * 9];
    const int t = threadIdx.x;
    for (int i = t; i < NLVL * 8; i += 256) lcnt[i] = 0;
    for (int i = t; i < NLVL * 9; i += 256) gs_s[i] = gstart[i];
    const int base = 1 + blockIdx.x * CHUNK;
    __syncthreads();
    for (int i = t; i < CHUNK; i += 256) {
        const int c = base + i;
        if (c < Nn) {
            const int e = edges[c];
            const int p = (c - 1) >> 1;
            const int l = 31 - __clz(p + 1);
            const int k = l * 8 + e;
            key_s[i] = (unsigned char)k;
            atomicAdd(&lcnt[k], 1);
        } else key_s[i] = 255;
    }
    __syncthreads();
    for (int i = t; i < NLVL * 8; i += 256) {
        const int n = lcnt[i];
        lbase[i] = n ? atomicAdd(&ctr[i], n) : 0;
        lcnt[i] = 0;
    }
    __syncthreads();
    for (int i = t; i < CHUNK; i += 256) {
        const int c = base + i;
        if (c >= Nn) continue;
        const int k = key_s[i];
        const int off = atomicAdd(&lcnt[k], 1);
        const int l = k >> 3, e = k & 7;
        const int pos = gs_s[l * 9 + e] + lbase[k] + off;
        perm[lvl_base_dev(l) + pos] = c;
    }
}

// ============ compose: Ccomp_e = data_W @ edge_W[e] (fp32), dcomp_e = data_b @ edge_W[e] + edge_b[e] ============
__global__ __launch_bounds__(256) void compose_kernel(
    const float* __restrict__ dW, const float* __restrict__ db,
    const float* __restrict__ eW, const float* __restrict__ eb,
    float* __restrict__ C, float* __restrict__ dv)
{
    __shared__ float aw_s[D * D];
    __shared__ float w_s[D * 32];
    const int t = threadIdx.x;
    const int e = blockIdx.x >> 2, cc = blockIdx.x & 3;
    for (int i = t; i < D * D / 4; i += 256) ((float4*)aw_s)[i] = ((const float4*)dW)[i];
    for (int i = t; i < D * 8; i += 256) {
        const int k = i >> 3, j4 = i & 7;
        ((float4*)w_s)[i] = ((const float4*)eW)[((size_t)e * D + k) * 32 + cc * 8 + j4];
    }
    __syncthreads();
    const int r2 = t >> 1, h = t & 1;
    float4 acc[4];
    #pragma unroll
    for (int m = 0; m < 4; m++) acc[m] = make_float4(0.f, 0.f, 0.f, 0.f);
    for (int k = 0; k < D; k++) {
        const float a = aw_s[r2 * D + k];
        #pragma unroll
        for (int m = 0; m < 4; m++) {
            const float4 w4 = ((const float4*)w_s)[k * 8 + h * 4 + m];
            acc[m].x += a * w4.x; acc[m].y += a * w4.y; acc[m].z += a * w4.z; acc[m].w += a * w4.w;
        }
    }
    #pragma unroll
    for (int m = 0; m < 4; m++)
        ((float4*)C)[((size_t)e * D + r2) * 32 + cc * 8 + h * 4 + m] = acc[m];
    if (t < 32) {
        float a2 = 0.f;
        for (int k = 0; k < D; k++) a2 += db[k] * w_s[k * 32 + t];
        dv[e * D + cc * 32 + t] = a2 + eb[e * D + cc * 32 + t];
    }
}

// ============ convert+transpose weights to bf16 [n][k] ============
__global__ __launch_bounds__(256) void convert_kernel(
    const float* __restrict__ eW, const float* __restrict__ Ccomp,
    const float* __restrict__ dW,
    unsigned short* __restrict__ ewt, unsigned short* __restrict__ cwt,
    unsigned short* __restrict__ dwt)
{
    __shared__ float lds[D * 129];
    const int b = blockIdx.x;
    const float* src = (b < 8) ? (eW + (size_t)b * D * D)
                     : (b < 16) ? (Ccomp + (size_t)(b - 8) * D * D)
                     : dW;
    unsigned short* dst = (b < 8) ? (ewt + (size_t)b * D * D)
                        : (b < 16) ? (cwt + (size_t)(b - 8) * D * D)
                        : dwt;
    const int t = threadIdx.x;
    for (int i = t; i < D * D / 4; i += 256) {
        float4 v = ((const float4*)src)[i];
        const int k = (i * 4) >> 7, n = (i * 4) & 127;
        lds[k * 129 + n]     = v.x;
        lds[k * 129 + n + 1] = v.y;
        lds[k * 129 + n + 2] = v.z;
        lds[k * 129 + n + 3] = v.w;
    }
    __syncthreads();
    const int n = t >> 1, h = t & 1;
    for (int k = 0; k < 64; k++)
        dst[(size_t)n * D + h * 64 + k] = f2bf(lds[(h * 64 + k) * 129 + n]);
}

// ============ merged leaf GEMM + embed (independent -> one launch, overlapped latency) ============
// blocks [0, LEAF_BLKS): leaf groups — rows = bf16(vecs[data[c]]), W=cwt[e], bias=dcomp[e],
//                        score = row.sv + s0; X[c] = rows @ W^T + bias.
// blocks [LEAF_BLKS, ..): embed — X[i] = bf16(vecs[data[i]] @ data_W + data_b) for internal i.
__global__ __launch_bounds__(256, 2) void leaf_embed_kernel(
    unsigned short* __restrict__ X,
    const float* __restrict__ vecs,
    const int* __restrict__ data,
    const int* __restrict__ perm,
    const int* __restrict__ gstart9,          // leaf level (pad128)
    const unsigned short* __restrict__ cwt,
    const float* __restrict__ dcomp,
    const float* __restrict__ sv, const float* __restrict__ s0p,
    const unsigned short* __restrict__ dwt,
    const float* __restrict__ db,
    float* __restrict__ out,
    int NI, int lbase_leaf)
{
    __shared__ unsigned short w_s[D * LDSTR];
    __shared__ unsigned short a_s[TS * LDSTR];
    __shared__ int prm[TS];
    const int t = threadIdx.x;
    const bool is_leaf = (blockIdx.x < LEAF_BLKS);

    if (is_leaf) {
        const int ts = blockIdx.x * TS;
        if (ts >= gstart9[8]) return;
        int e = 0;
        #pragma unroll
        for (int j = 1; j < 8; j++) if (ts >= gstart9[j]) e = j;
        if (t < TS) prm[t] = perm[lbase_leaf + ts + t];
        {   // stage W
            const int r = t >> 1, h = t & 1;
            const uint4* src = (const uint4*)(cwt + (size_t)e * D * D + (size_t)r * D + h * 64);
            uint4* dst = (uint4*)(w_s + r * LDSTR + h * 64);
            #pragma unroll
            for (int j = 0; j < 8; j++) dst[j] = src[j];
        }
        __syncthreads();
        {   // stage A (gather fp32 -> bf16) + fused score
            const int r = t >> 1, h = t & 1;
            const int c = prm[r];
            unsigned short* dst = a_s + r * LDSTR + h * 64;
            if (c >= 0) {
                const float4* src = (const float4*)(vecs + (size_t)data[c] * D + h * 64);
                float sc = 0.f;
                #pragma unroll
                for (int j = 0; j < 16; j++) {
                    float4 v = src[j];
                    const float4 s4 = ((const float4*)sv)[h * 16 + j];
                    sc += v.x * s4.x + v.y * s4.y + v.z * s4.z + v.w * s4.w;
                    uint2 o;
                    o.x = (unsigned)f2bf(v.x) | ((unsigned)f2bf(v.y) << 16);
                    o.y = (unsigned)f2bf(v.z) | ((unsigned)f2bf(v.w) << 16);
                    ((uint2*)dst)[j] = o;
                }
                sc += __shfl_xor(sc, 1, 64);
                if (h == 0) out[c] = sc + s0p[0];
            } else {
                #pragma unroll
                for (int j = 0; j < 8; j++) ((uint4*)dst)[j] = make_uint4(0u, 0u, 0u, 0u);
            }
        }
        __syncthreads();
        const int lane = t & 63, wv = t >> 6;
        const int cq = lane & 15, q = lane >> 4;
        const floatx4 z4 = {0.f, 0.f, 0.f, 0.f};
        floatx4 acc[8][2];
        #pragma unroll
        for (int i = 0; i < 8; i++) { acc[i][0] = z4; acc[i][1] = z4; }
        #pragma unroll
        for (int ks = 0; ks < 4; ks++) {
            shortx8 bfr[2];
            #pragma unroll
            for (int nl = 0; nl < 2; nl++) {
                const int n = (wv * 2 + nl) * 16 + cq;
                bfr[nl] = *(const shortx8*)(w_s + n * LDSTR + ks * 32 + q * 8);
            }
            #pragma unroll
            for (int mt = 0; mt < 8; mt++) {
                const shortx8 af = *(const shortx8*)(a_s + (mt * 16 + cq) * LDSTR + ks * 32 + q * 8);
                acc[mt][0] = __builtin_amdgcn_mfma_f32_16x16x32_bf16(af, bfr[0], acc[mt][0], 0, 0, 0);
                acc[mt][1] = __builtin_amdgcn_mfma_f32_16x16x32_bf16(af, bfr[1], acc[mt][1], 0, 0, 0);
            }
        }
        __syncthreads();
        #pragma unroll
        for (int nl = 0; nl < 2; nl++) {
            const int n = (wv * 2 + nl) * 16 + cq;
            const float bn = dcomp[(size_t)e * D + n];
            #pragma unroll
            for (int mt = 0; mt < 8; mt++) {
                #pragma unroll
                for (int r = 0; r < 4; r++) {
                    const int m = mt * 16 + q * 4 + r;
                    a_s[m * LDSTR + n] = f2bf(acc[mt][nl][r] + bn);
                }
            }
        }
        __syncthreads();
        {
            const int r = t >> 1, h = t & 1;
            const int c = prm[r];
            if (c >= 0) {
                uint4* dst = (uint4*)(X + (size_t)c * D + h * 64);
                const uint4* srcl = (const uint4*)(a_s + r * LDSTR + h * 64);
                #pragma unroll
                for (int j = 0; j < 8; j++) dst[j] = srcl[j];
            }
        }
    } else {
        // ---------------- embed path ----------------
        const int base = (blockIdx.x - LEAF_BLKS) * TS;
        {   // stage W
            const int r = t >> 1, h = t & 1;
            const uint4* src = (const uint4*)(dwt + (size_t)r * D + h * 64);
            uint4* dst = (uint4*)(w_s + r * LDSTR + h * 64);
            #pragma unroll
            for (int j = 0; j < 8; j++) dst[j] = src[j];
        }
        {   // stage A: gather fp32 -> bf16
            const int r = t >> 1, h = t & 1;
            const int node = base + r;
            unsigned short* dst = a_s + r * LDSTR + h * 64;
            if (node < NI) {
                const int idx = data[node];
                const float4* src = (const float4*)(vecs + (size_t)idx * D + h * 64);
                #pragma unroll
                for (int j = 0; j < 16; j++) {
                    float4 v = src[j];
                    uint2 o;
                    o.x = (unsigned)f2bf(v.x) | ((unsigned)f2bf(v.y) << 16);
                    o.y = (unsigned)f2bf(v.z) | ((unsigned)f2bf(v.w) << 16);
                    ((uint2*)dst)[j] = o;
                }
            } else {
                #pragma unroll
                for (int j = 0; j < 8; j++) ((uint4*)dst)[j] = make_uint4(0u, 0u, 0u, 0u);
            }
        }
        __syncthreads();
        const int lane = t & 63, wv = t >> 6;
        const int cq = lane & 15, q = lane >> 4;
        const floatx4 z4 = {0.f, 0.f, 0.f, 0.f};
        floatx4 acc[8][2];
        #pragma unroll
        for (int i = 0; i < 8; i++) { acc[i][0] = z4; acc[i][1] = z4; }
        #pragma unroll
        for (int ks = 0; ks < 4; ks++) {
            shortx8 bfr[2];
            #pragma unroll
            for (int nl = 0; nl < 2; nl++) {
                const int n = (wv * 2 + nl) * 16 + cq;
                bfr[nl] = *(const shortx8*)(w_s + n * LDSTR + ks * 32 + q * 8);
            }
            #pragma unroll
            for (int mt = 0; mt < 8; mt++) {
                const shortx8 af = *(const shortx8*)(a_s + (mt * 16 + cq) * LDSTR + ks * 32 + q * 8);
                acc[mt][0] = __builtin_amdgcn_mfma_f32_16x16x32_bf16(af, bfr[0], acc[mt][0], 0, 0, 0);
                acc[mt][1] = __builtin_amdgcn_mfma_f32_16x16x32_bf16(af, bfr[1], acc[mt][1], 0, 0, 0);
            }
        }
        __syncthreads();
        #pragma unroll
        for (int nl = 0; nl < 2; nl++) {
            const int n = (wv * 2 + nl) * 16 + cq;
            const float bn = db[n];
            #pragma unroll
            for (int mt = 0; mt < 8; mt++) {
                #pragma unroll
                for (int r = 0; r < 4; r++) {
                    const int m = mt * 16 + q * 4 + r;
                    a_s[m * LDSTR + n] = f2bf(acc[mt][nl][r] + bn);
                }
            }
        }
        __syncthreads();
        {
            const int r = t >> 1, h = t & 1;
            const int node = base + r;
            if (node < NI) {
                uint4* dst = (uint4*)(X + (size_t)node * D + h * 64);
                const uint4* srcl = (const uint4*)(a_s + r * LDSTR + h * 64);
                #pragma unroll
                for (int j = 0; j < 8; j++) dst[j] = srcl[j];
            }
        }
    }
}

// ============ big tree GEMM (levels 15..11, internal, pad128 groups) ============
__global__ __launch_bounds__(256, 2) void tree_gemm_kernel(
    unsigned short* __restrict__ X,
    const int* __restrict__ perm,
    const int* __restrict__ gstart9,
    const unsigned short* __restrict__ ewt,
    const float* __restrict__ eb,
    const float* __restrict__ svec,
    float* __restrict__ out,
    int lbase)
{
    __shared__ unsigned short w_s[D * LDSTR];
    __shared__ unsigned short a_s[TS * LDSTR];
    __shared__ int prm[TS];
    const int t = threadIdx.x;
    const int ts = blockIdx.x * TS;
    if (ts >= gstart9[8]) return;
    int e = 0;
    #pragma unroll
    for (int j = 1; j < 8; j++) if (ts >= gstart9[j]) e = j;
    if (t < TS) prm[t] = perm[lbase + ts + t];
    {   // stage W
        const int r = t >> 1, h = t & 1;
        const uint4* src = (const uint4*)(ewt + (size_t)e * D * D + (size_t)r * D + h * 64);
        uint4* dst = (uint4*)(w_s + r * LDSTR + h * 64);
        #pragma unroll
        for (int j = 0; j < 8; j++) dst[j] = src[j];
    }
    __syncthreads();
    {   // stage A: fused combine + score + ReLU
        const int r = t >> 1, h = t & 1;
        const int c = prm[r];
        unsigned short* dst = a_s + r * LDSTR + h * 64;
        if (c >= 0) {
            const uint4* xr = (const uint4*)(X + (size_t)c * D + h * 64);
            const uint4* ya = (const uint4*)(X + (size_t)(2 * c + 1) * D + h * 64);
            const uint4* yb = (const uint4*)(X + (size_t)(2 * c + 2) * D + h * 64);
            const float inv3 = 1.0f / 3.0f;
            float sc = 0.f;
            #pragma unroll
            for (int j = 0; j < 8; j++) {
                uint4 ra = xr[j], rb = ya[j], rc = yb[j];
                const unsigned* pa = (const unsigned*)&ra;
                const unsigned* pb = (const unsigned*)&rb;
                const unsigned* pc = (const unsigned*)&rc;
                unsigned ou[4];
                #pragma unroll
                for (int u = 0; u < 4; u++) {
                    const float h0 = (bf2f((unsigned short)pa[u]) + bf2f((unsigned short)pb[u])
                                    + bf2f((unsigned short)pc[u])) * inv3;
                    const float h1 = (bf2f((unsigned short)(pa[u] >> 16)) + bf2f((unsigned short)(pb[u] >> 16))
                                    + bf2f((unsigned short)(pc[u] >> 16))) * inv3;
                    const int n = h * 64 + j * 8 + u * 2;
                    sc += h0 * svec[n] + h1 * svec[n + 1];
                    unsigned short q0 = f2bf(h0), q1 = f2bf(h1);
                    q0 = (q0 & 0x8000u) ? 0 : q0;
                    q1 = (q1 & 0x8000u) ? 0 : q1;
                    ou[u] = (unsigned)q0 | ((unsigned)q1 << 16);
                }
                ((uint4*)dst)[j] = make_uint4(ou[0], ou[1], ou[2], ou[3]);
            }
            sc += __shfl_xor(sc, 1, 64);
            if (h == 0) out[c] = sc;
        } else {
            #pragma unroll
            for (int j = 0; j < 8; j++) ((uint4*)dst)[j] = make_uint4(0u, 0u, 0u, 0u);
        }
    }
    __syncthreads();
    const int lane = t & 63, wv = t >> 6;
    const int cq = lane & 15, q = lane >> 4;
    const floatx4 z4 = {0.f, 0.f, 0.f, 0.f};
    floatx4 acc[8][2];
    #pragma unroll
    for (int i = 0; i < 8; i++) { acc[i][0] = z4; acc[i][1] = z4; }
    #pragma unroll
    for (int ks = 0; ks < 4; ks++) {
        shortx8 bfr[2];
        #pragma unroll
        for (int nl = 0; nl < 2; nl++) {
            const int n = (wv * 2 + nl) * 16 + cq;
            bfr[nl] = *(const shortx8*)(w_s + n * LDSTR + ks * 32 + q * 8);
        }
        #pragma unroll
        for (int mt = 0; mt < 8; mt++) {
            const shortx8 af = *(const shortx8*)(a_s + (mt * 16 + cq) * LDSTR + ks * 32 + q * 8);
            acc[mt][0] = __builtin_amdgcn_mfma_f32_16x16x32_bf16(af, bfr[0], acc[mt][0], 0, 0, 0);
            acc[mt][1] = __builtin_amdgcn_mfma_f32_16x16x32_bf16(af, bfr[1], acc[mt][1], 0, 0, 0);
        }
    }
    __syncthreads();
    #pragma unroll
    for (int nl = 0; nl < 2; nl++) {
        const int n = (wv * 2 + nl) * 16 + cq;
        const float bn = eb[(size_t)e * D + n];
        #pragma unroll
        for (int mt = 0; mt < 8; mt++) {
            #pragma unroll
            for (int r = 0; r < 4; r++) {
                const int m = mt * 16 + q * 4 + r;
                a_s[m * LDSTR + n] = f2bf(acc[mt][nl][r] + bn);
            }
        }
    }
    __syncthreads();
    {
        const int r = t >> 1, h = t & 1;
        const int c = prm[r];
        if (c >= 0) {
            uint4* dst = (uint4*)(X + (size_t)c * D + h * 64);
            const uint4* srcl = (const uint4*)(a_s + r * LDSTR + h * 64);
            #pragma unroll
            for (int j = 0; j < 8; j++) dst[j] = srcl[j];
        }
    }
}

// ============ persistent top-levels kernel: levels 10..0 + root, one launch ============
// 16-row tiles, pad16 groups. W fragments read directly from global ewt (L2-hot, no LDS W).
// Device-scope sense barrier between levels (NB blocks, all co-resident).
__global__ __launch_bounds__(256, 1) void toplevels_kernel(
    unsigned short* __restrict__ X,
    const unsigned short* __restrict__ ewt,
    const float* __restrict__ eb,
    const int* __restrict__ perm,
    const int* __restrict__ gstart,
    const float* __restrict__ sW,
    float* __restrict__ out,
    int* __restrict__ bar)
{
    __shared__ unsigned short a_s[4][16 * LDSTR];
    __shared__ unsigned short y_s[4][16 * LDSTR];
    const int t = threadIdx.x;
    const int wv = t >> 6, lane = t & 63;
    const int gw = blockIdx.x * 4 + wv;
    const int NW = NB * 4;
    const float inv3 = 1.0f / 3.0f;
    int bi = 0;

    for (int l = 10; l >= 0; l--) {
        const int* g9 = gstart + l * 9;
        const int total = g9[8];
        const int lb = lvl_base_dev(l);
        for (int ti = gw; ti * 16 < total; ti += NW) {
            const int ts = ti * 16;
            int e = 0;
            #pragma unroll
            for (int j = 1; j < 8; j++) if (ts >= g9[j]) e = j;
            unsigned short* as = a_s[wv];
            unsigned short* ys = y_s[wv];
            const int r = lane >> 2, s = lane & 3;
            const int c = perm[lb + ts + r];
            // ---- stage: combine + score + ReLU (4 lanes per row, 32 elems each) ----
            if (c >= 0) {
                const uint4* xr = (const uint4*)(X + (size_t)c * D) + s * 4;
                const uint4* ya = (const uint4*)(X + (size_t)(2 * c + 1) * D) + s * 4;
                const uint4* yb = (const uint4*)(X + (size_t)(2 * c + 2) * D) + s * 4;
                uint4* dst = (uint4*)(as + r * LDSTR + s * 32);
                float sc = 0.f;
                #pragma unroll
                for (int j = 0; j < 4; j++) {
                    uint4 ra = xr[j], rb = ya[j], rc = yb[j];
                    const unsigned* pa = (const unsigned*)&ra;
                    const unsigned* pb = (const unsigned*)&rb;
                    const unsigned* pc = (const unsigned*)&rc;
                    unsigned ou[4];
                    #pragma unroll
                    for (int u = 0; u < 4; u++) {
                        const float h0 = (bf2f((unsigned short)pa[u]) + bf2f((unsigned short)pb[u])
                                        + bf2f((unsigned short)pc[u])) * inv3;
                        const float h1 = (bf2f((unsigned short)(pa[u] >> 16)) + bf2f((unsigned short)(pb[u] >> 16))
                                        + bf2f((unsigned short)(pc[u] >> 16))) * inv3;
                        const int n = s * 32 + j * 8 + u * 2;
                        sc += h0 * sW[n] + h1 * sW[n + 1];
                        unsigned short q0 = f2bf(h0), q1 = f2bf(h1);
                        q0 = (q0 & 0x8000u) ? 0 : q0;
                        q1 = (q1 & 0x8000u) ? 0 : q1;
                        ou[u] = (unsigned)q0 | ((unsigned)q1 << 16);
                    }
                    dst[j] = make_uint4(ou[0], ou[1], ou[2], ou[3]);
                }
                sc += __shfl_xor(sc, 1, 64);
                sc += __shfl_xor(sc, 2, 64);
                if (s == 0) out[c] = sc;
            } else {
                uint4* dst = (uint4*)(as + r * LDSTR + s * 32);
                #pragma unroll
                for (int j = 0; j < 4; j++) dst[j] = make_uint4(0u, 0u, 0u, 0u);
            }
            // ---- MFMA: 16 rows x 128 cols, B frags direct from global (L2-hot) ----
            const int cq = lane & 15, q = lane >> 4;
            const unsigned short* We = ewt + (size_t)e * D * D;
            const floatx4 z4 = {0.f, 0.f, 0.f, 0.f};
            floatx4 acc[8];
            #pragma unroll
            for (int i = 0; i < 8; i++) acc[i] = z4;
            #pragma unroll
            for (int ks = 0; ks < 4; ks++) {
                const shortx8 af = *(const shortx8*)(as + cq * LDSTR + ks * 32 + q * 8);
                #pragma unroll
                for (int nt = 0; nt < 8; nt++) {
                    const shortx8 bf = *(const shortx8*)(We + (size_t)(nt * 16 + cq) * D + ks * 32 + q * 8);
                    acc[nt] = __builtin_amdgcn_mfma_f32_16x16x32_bf16(af, bf, acc[nt], 0, 0, 0);
                }
            }
            // ---- epilogue: bias -> y_s (transpose), then vector writeback ----
            #pragma unroll
            for (int nt = 0; nt < 8; nt++) {
                const int n = nt * 16 + cq;
                const float bn = eb[(size_t)e * D + n];
                #pragma unroll
                for (int rg = 0; rg < 4; rg++)
                    ys[(q * 4 + rg) * LDSTR + n] = f2bf(acc[nt][rg] + bn);
            }
            if (c >= 0) {
                uint4* dst = (uint4*)(X + (size_t)c * D) + s * 4;
                const uint4* srcl = (const uint4*)(ys + r * LDSTR + s * 32);
                #pragma unroll
                for (int j = 0; j < 4; j++) dst[j] = srcl[j];
            }
        }
        // ---- grid barrier ----
        __threadfence();
        __syncthreads();
        if (t == 0) {
            __hip_atomic_fetch_add(&bar[bi], 1, __ATOMIC_RELEASE, __HIP_MEMORY_SCOPE_AGENT);
            while (__hip_atomic_load(&bar[bi], __ATOMIC_ACQUIRE, __HIP_MEMORY_SCOPE_AGENT) < NB) {
                __builtin_amdgcn_s_sleep(1);
            }
        }
        __syncthreads();
        bi++;
    }
    // ---- root score ----
    if (blockIdx.x == 0 && t < 64) {
        float sc = 0.f;
        #pragma unroll
        for (int u = 0; u < 2; u++) {
            const int n = t * 2 + u;
            const float hf = (bf2f(X[n]) + bf2f(X[D + n]) + bf2f(X[2 * D + n])) * inv3;
            sc += hf * sW[n];
        }
        #pragma unroll
        for (int off = 32; off > 0; off >>= 1) sc += __shfl_down(sc, off, 64);
        if (t == 0) out[0] = sc;
    }
}

extern "C" void kernel_launch(void* const* d_in, const int* in_sizes, int n_in,
                              void* d_out, int out_size, void* d_ws, size_t ws_size,
                              hipStream_t stream) {
    const int*   data      = (const int*)d_in[0];
    const int*   edges     = (const int*)d_in[1];
    const float* data_vecs = (const float*)d_in[2];
    const float* data_W    = (const float*)d_in[3];
    const float* data_b    = (const float*)d_in[4];
    const float* edge_W    = (const float*)d_in[5];
    const float* edge_b    = (const float*)d_in[6];
    const float* score_W   = (const float*)d_in[7];
    float* out = (float*)d_out;

    const int Nn = in_sizes[0];          // 2^18 - 1
    const int NI = Nn >> 1;              // internal nodes: 2^17 - 1
    const int PERM_TOTAL = (Nn - 1) + LVLPAD * NLVL;

    char* w = (char*)d_ws;
    size_t off = 0;
    unsigned short* X = (unsigned short*)(w + off); off += (size_t)Nn * D * 2;
    int* perm = (int*)(w + off);  off += (size_t)PERM_TOTAL * 4;
    off = (off + 255) & ~(size_t)255;
    int* gstart = (int*)(w + off); off += NLVL * 9 * 4;
    int* gcnt   = (int*)(w + off); off += NLVL * 8 * 4;
    int* ctr    = (int*)(w + off); off += NLVL * 8 * 4;
    int* bar    = (int*)(w + off); off += 32 * 4;
    const size_t zero_ints = NLVL * 9 + NLVL * 8 + NLVL * 8 + 32;
    off = (off + 255) & ~(size_t)255;
    float* Ccomp = (float*)(w + off); off += (size_t)8 * D * D * 4;
    float* dcomp = (float*)(w + off); off += 8 * D * 4;
    float* sv    = (float*)(w + off); off += D * 4;
    float* s0    = (float*)(w + off); off += 256;
    off = (off + 255) & ~(size_t)255;
    unsigned short* ewt = (unsigned short*)(w + off); off += (size_t)8 * D * D * 2;
    unsigned short* cwt = (unsigned short*)(w + off); off += (size_t)8 * D * D * 2;
    unsigned short* dwt = (unsigned short*)(w + off); off += (size_t)D * D * 2;

    hipMemsetAsync(perm, 0xFF, (size_t)PERM_TOTAL * 4, stream);
    hipMemsetAsync(gstart, 0, zero_ints * 4, stream);

    count_kernel<<<128, 256, 0, stream>>>(edges, gcnt, Nn);
    prefix_sv_kernel<<<1, 256, 0, stream>>>(gcnt, gstart, data_W, data_b, score_W, sv, s0);
    place_kernel<<<(Nn - 1 + CHUNK - 1) / CHUNK, 256, 0, stream>>>(edges, gstart, ctr, perm, Nn);
    compose_kernel<<<32, 256, 0, stream>>>(data_W, data_b, edge_W, edge_b, Ccomp, dcomp);
    convert_kernel<<<17, 256, 0, stream>>>(edge_W, Ccomp, data_W, ewt, cwt, dwt);

    // merged leaf GEMM (level 16) + embed, one launch
    {
        const int embed_blks = (NI + TS - 1) / TS;
        const int lbase_leaf = ((2 << 16) - 2) + LVLPAD * 16;
        leaf_embed_kernel<<<LEAF_BLKS + embed_blks, 256, 0, stream>>>(
            X, data_vecs, data, perm, gstart + 16 * 9,
            cwt, dcomp, sv, s0, dwt, data_b, out, NI, lbase_leaf);
    }

    // big internal levels 15..11
    for (int l = 15; l >= 11; l--) {
        const int M = 2 << l;
        const int lbase = ((2 << l) - 2) + LVLPAD * l;
        tree_gemm_kernel<<<M / TS + 8, 256, 0, stream>>>(
            X, perm, gstart + l * 9, ewt, edge_b, score_W, out, lbase);
    }

    // persistent kernel: levels 10..0 + root
    toplevels_kernel<<<NB, 256, 0, stream>>>(X, ewt, edge_b, perm, gstart, score_W, out, bar);
}

// Round 6
// 346.801 us; speedup vs baseline: 1.2891x; 1.2891x over previous
//
#include <hip/hip_runtime.h>

#define D 128
#define NLVL 17          // parent levels 0..16
#define TS 128           // rows per big GEMM tile
#define LVLPAD 1024      // per-level perm slack for group padding
#define LDSTR 136        // LDS row stride in bf16 elems (272B: conflict-free b128)
#define LEAF_BLKS 1032   // ceil((131072 + 8*127)/128)

typedef float  floatx4 __attribute__((ext_vector_type(4)));
typedef short  shortx8 __attribute__((ext_vector_type(8)));

__device__ __forceinline__ unsigned short f2bf(float f) {   // RNE fp32->bf16
    unsigned u = __float_as_uint(f);
    u += 0x7FFFu + ((u >> 16) & 1u);
    return (unsigned short)(u >> 16);
}
__device__ __forceinline__ float bf2f(unsigned short h) {
    return __uint_as_float(((unsigned)h) << 16);
}
__device__ __forceinline__ int lvl_base_dev(int l) { return ((2 << l) - 2) + LVLPAD * l; }

// ============ sort step 1: per-(level,edge) counts ============
__global__ __launch_bounds__(256) void count_kernel(
    const int* __restrict__ edges, int* __restrict__ gcnt, int Nn)
{
    __shared__ int lc[NLVL * 8];
    const int t = threadIdx.x;
    for (int i = t; i < NLVL * 8; i += 256) lc[i] = 0;
    __syncthreads();
    for (int c = 1 + blockIdx.x * 256 + t; c < Nn; c += gridDim.x * 256) {
        const int e = edges[c];
        const int p = (c - 1) >> 1;
        const int l = 31 - __clz(p + 1);
        if (l >= 11) atomicAdd(&lc[l * 8 + e], 1);   // levels <=10 handled by subtree kernels
    }
    __syncthreads();
    for (int i = t; i < NLVL * 8; i += 256) if (lc[i]) atomicAdd(&gcnt[i], lc[i]);
}

// ============ sort step 2: padded prefix (+ sv = data_W @ score_W, s0 = data_b . score_W) ============
__global__ __launch_bounds__(256) void prefix_sv_kernel(
    const int* __restrict__ gcnt, int* __restrict__ gstart,
    const float* __restrict__ dW, const float* __restrict__ db,
    const float* __restrict__ sWs, float* __restrict__ sv, float* __restrict__ s0)
{
    __shared__ float red[256];
    const int t = threadIdx.x;
    if (t < D) {
        float acc = 0.f;
        for (int j = 0; j < D; j++) acc += dW[t * D + j] * sWs[j];
        sv[t] = acc;
    }
    red[t] = (t < D) ? db[t] * sWs[t] : 0.f;
    __syncthreads();
    for (int s = 128; s > 0; s >>= 1) { if (t < s) red[t] += red[t + s]; __syncthreads(); }
    if (t == 0) {
        *s0 = red[0];
        for (int l = 0; l < NLVL; l++) {
            int acc = 0;
            for (int e = 0; e < 8; e++) {
                gstart[l * 9 + e] = acc;
                if (l >= 11) acc = (acc + gcnt[l * 8 + e] + (TS - 1)) & ~(TS - 1);
            }
            gstart[l * 9 + 8] = acc;
        }
    }
}

// ============ sort step 3: placement (levels >= 11 only) ============
#define CHUNK 2048
__global__ __launch_bounds__(256) void place_kernel(
    const int* __restrict__ edges, const int* __restrict__ gstart,
    int* __restrict__ ctr, int* __restrict__ perm, int Nn)
{
    __shared__ unsigned char key_s[CHUNK];
    __shared__ int lcnt[NLVL * 8], lbase[NLVL * 8];
    __shared__ int gs_s[NLVL * 9];
    const int t = threadIdx.x;
    for (int i = t; i < NLVL * 8; i += 256) lcnt[i] = 0;
    for (int i = t; i < NLVL * 9; i += 256) gs_s[i] = gstart[i];
    const int base = 1 + blockIdx.x * CHUNK;
    __syncthreads();
    for (int i = t; i < CHUNK; i += 256) {
        const int c = base + i;
        if (c < Nn) {
            const int e = edges[c];
            const int p = (c - 1) >> 1;
            const int l = 31 - __clz(p + 1);
            if (l >= 11) {
                const int k = l * 8 + e;
                key_s[i] = (unsigned char)k;
                atomicAdd(&lcnt[k], 1);
            } else key_s[i] = 255;
        } else key_s[i] = 255;
    }
    __syncthreads();
    for (int i = t; i < NLVL * 8; i += 256) {
        const int n = lcnt[i];
        lbase[i] = n ? atomicAdd(&ctr[i], n) : 0;
        lcnt[i] = 0;
    }
    __syncthreads();
    for (int i = t; i < CHUNK; i += 256) {
        const int c = base + i;
        if (c >= Nn) continue;
        const int k = key_s[i];
        if (k == 255) continue;
        const int off = atomicAdd(&lcnt[k], 1);
        const int l = k >> 3, e = k & 7;
        const int pos = gs_s[l * 9 + e] + lbase[k] + off;
        perm[lvl_base_dev(l) + pos] = c;
    }
}

// ============ compose: Ccomp_e = data_W @ edge_W[e] (fp32), dcomp_e = data_b @ edge_W[e] + edge_b[e] ============
__global__ __launch_bounds__(256) void compose_kernel(
    const float* __restrict__ dW, const float* __restrict__ db,
    const float* __restrict__ eW, const float* __restrict__ eb,
    float* __restrict__ C, float* __restrict__ dv)
{
    __shared__ float aw_s[D * D];
    __shared__ float w_s[D * 32];
    const int t = threadIdx.x;
    const int e = blockIdx.x >> 2, cc = blockIdx.x & 3;
    for (int i = t; i < D * D / 4; i += 256) ((float4*)aw_s)[i] = ((const float4*)dW)[i];
    for (int i = t; i < D * 8; i += 256) {
        const int k = i >> 3, j4 = i & 7;
        ((float4*)w_s)[i] = ((const float4*)eW)[((size_t)e * D + k) * 32 + cc * 8 + j4];
    }
    __syncthreads();
    const int r2 = t >> 1, h = t & 1;
    float4 acc[4];
    #pragma unroll
    for (int m = 0; m < 4; m++) acc[m] = make_float4(0.f, 0.f, 0.f, 0.f);
    for (int k = 0; k < D; k++) {
        const float a = aw_s[r2 * D + k];
        #pragma unroll
        for (int m = 0; m < 4; m++) {
            const float4 w4 = ((const float4*)w_s)[k * 8 + h * 4 + m];
            acc[m].x += a * w4.x; acc[m].y += a * w4.y; acc[m].z += a * w4.z; acc[m].w += a * w4.w;
        }
    }
    #pragma unroll
    for (int m = 0; m < 4; m++)
        ((float4*)C)[((size_t)e * D + r2) * 32 + cc * 8 + h * 4 + m] = acc[m];
    if (t < 32) {
        float a2 = 0.f;
        for (int k = 0; k < D; k++) a2 += db[k] * w_s[k * 32 + t];
        dv[e * D + cc * 32 + t] = a2 + eb[e * D + cc * 32 + t];
    }
}

// ============ convert+transpose weights to bf16 [n][k] ============
__global__ __launch_bounds__(256) void convert_kernel(
    const float* __restrict__ eW, const float* __restrict__ Ccomp,
    const float* __restrict__ dW,
    unsigned short* __restrict__ ewt, unsigned short* __restrict__ cwt,
    unsigned short* __restrict__ dwt)
{
    __shared__ float lds[D * 129];
    const int b = blockIdx.x;
    const float* src = (b < 8) ? (eW + (size_t)b * D * D)
                     : (b < 16) ? (Ccomp + (size_t)(b - 8) * D * D)
                     : dW;
    unsigned short* dst = (b < 8) ? (ewt + (size_t)b * D * D)
                        : (b < 16) ? (cwt + (size_t)(b - 8) * D * D)
                        : dwt;
    const int t = threadIdx.x;
    for (int i = t; i < D * D / 4; i += 256) {
        float4 v = ((const float4*)src)[i];
        const int k = (i * 4) >> 7, n = (i * 4) & 127;
        lds[k * 129 + n]     = v.x;
        lds[k * 129 + n + 1] = v.y;
        lds[k * 129 + n + 2] = v.z;
        lds[k * 129 + n + 3] = v.w;
    }
    __syncthreads();
    const int n = t >> 1, h = t & 1;
    for (int k = 0; k < 64; k++)
        dst[(size_t)n * D + h * 64 + k] = f2bf(lds[(h * 64 + k) * 129 + n]);
}

// ============ merged leaf GEMM + embed ============
__global__ __launch_bounds__(256, 2) void leaf_embed_kernel(
    unsigned short* __restrict__ X,
    const float* __restrict__ vecs,
    const int* __restrict__ data,
    const int* __restrict__ perm,
    const int* __restrict__ gstart9,
    const unsigned short* __restrict__ cwt,
    const float* __restrict__ dcomp,
    const float* __restrict__ sv, const float* __restrict__ s0p,
    const unsigned short* __restrict__ dwt,
    const float* __restrict__ db,
    float* __restrict__ out,
    int NI, int lbase_leaf)
{
    __shared__ unsigned short w_s[D * LDSTR];
    __shared__ unsigned short a_s[TS * LDSTR];
    __shared__ int prm[TS];
    const int t = threadIdx.x;
    const bool is_leaf = (blockIdx.x < LEAF_BLKS);

    if (is_leaf) {
        const int ts = blockIdx.x * TS;
        if (ts >= gstart9[8]) return;
        int e = 0;
        #pragma unroll
        for (int j = 1; j < 8; j++) if (ts >= gstart9[j]) e = j;
        if (t < TS) prm[t] = perm[lbase_leaf + ts + t];
        {   // stage W
            const int r = t >> 1, h = t & 1;
            const uint4* src = (const uint4*)(cwt + (size_t)e * D * D + (size_t)r * D + h * 64);
            uint4* dst = (uint4*)(w_s + r * LDSTR + h * 64);
            #pragma unroll
            for (int j = 0; j < 8; j++) dst[j] = src[j];
        }
        __syncthreads();
        {   // stage A + fused score
            const int r = t >> 1, h = t & 1;
            const int c = prm[r];
            unsigned short* dst = a_s + r * LDSTR + h * 64;
            if (c >= 0) {
                const float4* src = (const float4*)(vecs + (size_t)data[c] * D + h * 64);
                float sc = 0.f;
                #pragma unroll
                for (int j = 0; j < 16; j++) {
                    float4 v = src[j];
                    const float4 s4 = ((const float4*)sv)[h * 16 + j];
                    sc += v.x * s4.x + v.y * s4.y + v.z * s4.z + v.w * s4.w;
                    uint2 o;
                    o.x = (unsigned)f2bf(v.x) | ((unsigned)f2bf(v.y) << 16);
                    o.y = (unsigned)f2bf(v.z) | ((unsigned)f2bf(v.w) << 16);
                    ((uint2*)dst)[j] = o;
                }
                sc += __shfl_xor(sc, 1, 64);
                if (h == 0) out[c] = sc + s0p[0];
            } else {
                #pragma unroll
                for (int j = 0; j < 8; j++) ((uint4*)dst)[j] = make_uint4(0u, 0u, 0u, 0u);
            }
        }
        __syncthreads();
        const int lane = t & 63, wv = t >> 6;
        const int cq = lane & 15, q = lane >> 4;
        const floatx4 z4 = {0.f, 0.f, 0.f, 0.f};
        floatx4 acc[8][2];
        #pragma unroll
        for (int i = 0; i < 8; i++) { acc[i][0] = z4; acc[i][1] = z4; }
        #pragma unroll
        for (int ks = 0; ks < 4; ks++) {
            shortx8 bfr[2];
            #pragma unroll
            for (int nl = 0; nl < 2; nl++) {
                const int n = (wv * 2 + nl) * 16 + cq;
                bfr[nl] = *(const shortx8*)(w_s + n * LDSTR + ks * 32 + q * 8);
            }
            #pragma unroll
            for (int mt = 0; mt < 8; mt++) {
                const shortx8 af = *(const shortx8*)(a_s + (mt * 16 + cq) * LDSTR + ks * 32 + q * 8);
                acc[mt][0] = __builtin_amdgcn_mfma_f32_16x16x32_bf16(af, bfr[0], acc[mt][0], 0, 0, 0);
                acc[mt][1] = __builtin_amdgcn_mfma_f32_16x16x32_bf16(af, bfr[1], acc[mt][1], 0, 0, 0);
            }
        }
        __syncthreads();
        #pragma unroll
        for (int nl = 0; nl < 2; nl++) {
            const int n = (wv * 2 + nl) * 16 + cq;
            const float bn = dcomp[(size_t)e * D + n];
            #pragma unroll
            for (int mt = 0; mt < 8; mt++) {
                #pragma unroll
                for (int r = 0; r < 4; r++) {
                    const int m = mt * 16 + q * 4 + r;
                    a_s[m * LDSTR + n] = f2bf(acc[mt][nl][r] + bn);
                }
            }
        }
        __syncthreads();
        {
            const int r = t >> 1, h = t & 1;
            const int c = prm[r];
            if (c >= 0) {
                uint4* dst = (uint4*)(X + (size_t)c * D + h * 64);
                const uint4* srcl = (const uint4*)(a_s + r * LDSTR + h * 64);
                #pragma unroll
                for (int j = 0; j < 8; j++) dst[j] = srcl[j];
            }
        }
    } else {
        // ---------------- embed path ----------------
        const int base = (blockIdx.x - LEAF_BLKS) * TS;
        {   // stage W
            const int r = t >> 1, h = t & 1;
            const uint4* src = (const uint4*)(dwt + (size_t)r * D + h * 64);
            uint4* dst = (uint4*)(w_s + r * LDSTR + h * 64);
            #pragma unroll
            for (int j = 0; j < 8; j++) dst[j] = src[j];
        }
        {   // stage A: gather fp32 -> bf16
            const int r = t >> 1, h = t & 1;
            const int node = base + r;
            unsigned short* dst = a_s + r * LDSTR + h * 64;
            if (node < NI) {
                const int idx = data[node];
                const float4* src = (const float4*)(vecs + (size_t)idx * D + h * 64);
                #pragma unroll
                for (int j = 0; j < 16; j++) {
                    float4 v = src[j];
                    uint2 o;
                    o.x = (unsigned)f2bf(v.x) | ((unsigned)f2bf(v.y) << 16);
                    o.y = (unsigned)f2bf(v.z) | ((unsigned)f2bf(v.w) << 16);
                    ((uint2*)dst)[j] = o;
                }
            } else {
                #pragma unroll
                for (int j = 0; j < 8; j++) ((uint4*)dst)[j] = make_uint4(0u, 0u, 0u, 0u);
            }
        }
        __syncthreads();
        const int lane = t & 63, wv = t >> 6;
        const int cq = lane & 15, q = lane >> 4;
        const floatx4 z4 = {0.f, 0.f, 0.f, 0.f};
        floatx4 acc[8][2];
        #pragma unroll
        for (int i = 0; i < 8; i++) { acc[i][0] = z4; acc[i][1] = z4; }
        #pragma unroll
        for (int ks = 0; ks < 4; ks++) {
            shortx8 bfr[2];
            #pragma unroll
            for (int nl = 0; nl < 2; nl++) {
                const int n = (wv * 2 + nl) * 16 + cq;
                bfr[nl] = *(const shortx8*)(w_s + n * LDSTR + ks * 32 + q * 8);
            }
            #pragma unroll
            for (int mt = 0; mt < 8; mt++) {
                const shortx8 af = *(const shortx8*)(a_s + (mt * 16 + cq) * LDSTR + ks * 32 + q * 8);
                acc[mt][0] = __builtin_amdgcn_mfma_f32_16x16x32_bf16(af, bfr[0], acc[mt][0], 0, 0, 0);
                acc[mt][1] = __builtin_amdgcn_mfma_f32_16x16x32_bf16(af, bfr[1], acc[mt][1], 0, 0, 0);
            }
        }
        __syncthreads();
        #pragma unroll
        for (int nl = 0; nl < 2; nl++) {
            const int n = (wv * 2 + nl) * 16 + cq;
            const float bn = db[n];
            #pragma unroll
            for (int mt = 0; mt < 8; mt++) {
                #pragma unroll
                for (int r = 0; r < 4; r++) {
                    const int m = mt * 16 + q * 4 + r;
                    a_s[m * LDSTR + n] = f2bf(acc[mt][nl][r] + bn);
                }
            }
        }
        __syncthreads();
        {
            const int r = t >> 1, h = t & 1;
            const int node = base + r;
            if (node < NI) {
                uint4* dst = (uint4*)(X + (size_t)node * D + h * 64);
                const uint4* srcl = (const uint4*)(a_s + r * LDSTR + h * 64);
                #pragma unroll
                for (int j = 0; j < 8; j++) dst[j] = srcl[j];
            }
        }
    }
}

// ============ big tree GEMM (levels 15..11, internal, pad128 groups) ============
__global__ __launch_bounds__(256, 2) void tree_gemm_kernel(
    unsigned short* __restrict__ X,
    const int* __restrict__ perm,
    const int* __restrict__ gstart9,
    const unsigned short* __restrict__ ewt,
    const float* __restrict__ eb,
    const float* __restrict__ svec,
    float* __restrict__ out,
    int lbase)
{
    __shared__ unsigned short w_s[D * LDSTR];
    __shared__ unsigned short a_s[TS * LDSTR];
    __shared__ int prm[TS];
    const int t = threadIdx.x;
    const int ts = blockIdx.x * TS;
    if (ts >= gstart9[8]) return;
    int e = 0;
    #pragma unroll
    for (int j = 1; j < 8; j++) if (ts >= gstart9[j]) e = j;
    if (t < TS) prm[t] = perm[lbase + ts + t];
    {   // stage W
        const int r = t >> 1, h = t & 1;
        const uint4* src = (const uint4*)(ewt + (size_t)e * D * D + (size_t)r * D + h * 64);
        uint4* dst = (uint4*)(w_s + r * LDSTR + h * 64);
        #pragma unroll
        for (int j = 0; j < 8; j++) dst[j] = src[j];
    }
    __syncthreads();
    {   // stage A: fused combine + score + ReLU
        const int r = t >> 1, h = t & 1;
        const int c = prm[r];
        unsigned short* dst = a_s + r * LDSTR + h * 64;
        if (c >= 0) {
            const uint4* xr = (const uint4*)(X + (size_t)c * D + h * 64);
            const uint4* ya = (const uint4*)(X + (size_t)(2 * c + 1) * D + h * 64);
            const uint4* yb = (const uint4*)(X + (size_t)(2 * c + 2) * D + h * 64);
            const float inv3 = 1.0f / 3.0f;
            float sc = 0.f;
            #pragma unroll
            for (int j = 0; j < 8; j++) {
                uint4 ra = xr[j], rb = ya[j], rc = yb[j];
                const unsigned* pa = (const unsigned*)&ra;
                const unsigned* pb = (const unsigned*)&rb;
                const unsigned* pc = (const unsigned*)&rc;
                unsigned ou[4];
                #pragma unroll
                for (int u = 0; u < 4; u++) {
                    const float h0 = (bf2f((unsigned short)pa[u]) + bf2f((unsigned short)pb[u])
                                    + bf2f((unsigned short)pc[u])) * inv3;
                    const float h1 = (bf2f((unsigned short)(pa[u] >> 16)) + bf2f((unsigned short)(pb[u] >> 16))
                                    + bf2f((unsigned short)(pc[u] >> 16))) * inv3;
                    const int n = h * 64 + j * 8 + u * 2;
                    sc += h0 * svec[n] + h1 * svec[n + 1];
                    unsigned short q0 = f2bf(h0), q1 = f2bf(h1);
                    q0 = (q0 & 0x8000u) ? 0 : q0;
                    q1 = (q1 & 0x8000u) ? 0 : q1;
                    ou[u] = (unsigned)q0 | ((unsigned)q1 << 16);
                }
                ((uint4*)dst)[j] = make_uint4(ou[0], ou[1], ou[2], ou[3]);
            }
            sc += __shfl_xor(sc, 1, 64);
            if (h == 0) out[c] = sc;
        } else {
            #pragma unroll
            for (int j = 0; j < 8; j++) ((uint4*)dst)[j] = make_uint4(0u, 0u, 0u, 0u);
        }
    }
    __syncthreads();
    const int lane = t & 63, wv = t >> 6;
    const int cq = lane & 15, q = lane >> 4;
    const floatx4 z4 = {0.f, 0.f, 0.f, 0.f};
    floatx4 acc[8][2];
    #pragma unroll
    for (int i = 0; i < 8; i++) { acc[i][0] = z4; acc[i][1] = z4; }
    #pragma unroll
    for (int ks = 0; ks < 4; ks++) {
        shortx8 bfr[2];
        #pragma unroll
        for (int nl = 0; nl < 2; nl++) {
            const int n = (wv * 2 + nl) * 16 + cq;
            bfr[nl] = *(const shortx8*)(w_s + n * LDSTR + ks * 32 + q * 8);
        }
        #pragma unroll
        for (int mt = 0; mt < 8; mt++) {
            const shortx8 af = *(const shortx8*)(a_s + (mt * 16 + cq) * LDSTR + ks * 32 + q * 8);
            acc[mt][0] = __builtin_amdgcn_mfma_f32_16x16x32_bf16(af, bfr[0], acc[mt][0], 0, 0, 0);
            acc[mt][1] = __builtin_amdgcn_mfma_f32_16x16x32_bf16(af, bfr[1], acc[mt][1], 0, 0, 0);
        }
    }
    __syncthreads();
    #pragma unroll
    for (int nl = 0; nl < 2; nl++) {
        const int n = (wv * 2 + nl) * 16 + cq;
        const float bn = eb[(size_t)e * D + n];
        #pragma unroll
        for (int mt = 0; mt < 8; mt++) {
            #pragma unroll
            for (int r = 0; r < 4; r++) {
                const int m = mt * 16 + q * 4 + r;
                a_s[m * LDSTR + n] = f2bf(acc[mt][nl][r] + bn);
            }
        }
    }
    __syncthreads();
    {
        const int r = t >> 1, h = t & 1;
        const int c = prm[r];
        if (c >= 0) {
            uint4* dst = (uint4*)(X + (size_t)c * D + h * 64);
            const uint4* srcl = (const uint4*)(a_s + r * LDSTR + h * 64);
            #pragma unroll
            for (int j = 0; j < 8; j++) dst[j] = srcl[j];
        }
    }
}

// ============ subtree kernel: block owns subtree rooted at (rbase + blockIdx), ============
// processes nlev depths bottom-up with only __syncthreads between depths.
// Per node n (one wave): h = (X[n] + X[2n+1] + X[2n+2])/3, out[n] = h . sW,
// x = ReLU(h), X[n] = x @ edge_W[edges[n]] + edge_b (fp32 W direct, VALU matvec).
// n == 0 (root): score only, no matvec/store.
__global__ __launch_bounds__(256) void sub_kernel(
    unsigned short* __restrict__ X,
    const float* __restrict__ eW,     // original fp32 [8][128][128] (k-major)
    const float* __restrict__ eb,
    const int* __restrict__ edges,
    const float* __restrict__ sW,
    float* __restrict__ out,
    int rbase, int nlev)
{
    __shared__ __align__(16) float xbuf[4][D];
    const int t = threadIdx.x, wv = t >> 6, lane = t & 63;
    const int u = rbase + blockIdx.x;
    const int j2 = lane * 2;
    const float inv3 = 1.0f / 3.0f;

    for (int lev = nlev - 1; lev >= 0; lev--) {
        const int first = ((u + 1) << lev) - 1;
        const int cnt = 1 << lev;
        for (int i = wv; i < cnt; i += 4) {
            const int n = first + i;
            // ---- combine + score ----
            const unsigned ra = *(const unsigned*)(X + (size_t)n * D + j2);
            const unsigned rb = *(const unsigned*)(X + (size_t)(2 * n + 1) * D + j2);
            const unsigned rc = *(const unsigned*)(X + (size_t)(2 * n + 2) * D + j2);
            const float h0 = (bf2f((unsigned short)ra) + bf2f((unsigned short)rb)
                            + bf2f((unsigned short)rc)) * inv3;
            const float h1 = (bf2f((unsigned short)(ra >> 16)) + bf2f((unsigned short)(rb >> 16))
                            + bf2f((unsigned short)(rc >> 16))) * inv3;
            float sc = h0 * sW[j2] + h1 * sW[j2 + 1];
            #pragma unroll
            for (int o = 32; o > 0; o >>= 1) sc += __shfl_xor(sc, o, 64);
            if (lane == 0) out[n] = sc;
            if (n == 0) continue;   // root: no matvec
            // ---- ReLU -> wave-private LDS broadcast buffer ----
            float2 x2 = make_float2(fmaxf(h0, 0.f), fmaxf(h1, 0.f));
            *(float2*)(xbuf[wv] + j2) = x2;
            const int e = edges[n];
            const float* W = eW + (size_t)e * D * D;
            float y0 = 0.f, y1 = 0.f;
            #pragma unroll 8
            for (int k4 = 0; k4 < 32; k4++) {
                const float4 xk = *(const float4*)(xbuf[wv] + k4 * 4);
                const float2 w0 = *(const float2*)(W + (size_t)(k4 * 4 + 0) * D + j2);
                const float2 w1 = *(const float2*)(W + (size_t)(k4 * 4 + 1) * D + j2);
                const float2 w2 = *(const float2*)(W + (size_t)(k4 * 4 + 2) * D + j2);
                const float2 w3 = *(const float2*)(W + (size_t)(k4 * 4 + 3) * D + j2);
                y0 += xk.x * w0.x + xk.y * w1.x + xk.z * w2.x + xk.w * w3.x;
                y1 += xk.x * w0.y + xk.y * w1.y + xk.z * w2.y + xk.w * w3.y;
            }
            y0 += eb[e * D + j2];
            y1 += eb[e * D + j2 + 1];
            const unsigned o = (unsigned)f2bf(y0) | ((unsigned)f2bf(y1) << 16);
            *(unsigned*)(X + (size_t)n * D + j2) = o;
        }
        __syncthreads();
    }
}

extern "C" void kernel_launch(void* const* d_in, const int* in_sizes, int n_in,
                              void* d_out, int out_size, void* d_ws, size_t ws_size,
                              hipStream_t stream) {
    const int*   data      = (const int*)d_in[0];
    const int*   edges     = (const int*)d_in[1];
    const float* data_vecs = (const float*)d_in[2];
    const float* data_W    = (const float*)d_in[3];
    const float* data_b    = (const float*)d_in[4];
    const float* edge_W    = (const float*)d_in[5];
    const float* edge_b    = (const float*)d_in[6];
    const float* score_W   = (const float*)d_in[7];
    float* out = (float*)d_out;

    const int Nn = in_sizes[0];          // 2^18 - 1
    const int NI = Nn >> 1;              // internal nodes: 2^17 - 1
    const int PERM_TOTAL = (Nn - 1) + LVLPAD * NLVL;

    char* w = (char*)d_ws;
    size_t off = 0;
    unsigned short* X = (unsigned short*)(w + off); off += (size_t)Nn * D * 2;
    int* perm = (int*)(w + off);  off += (size_t)PERM_TOTAL * 4;
    off = (off + 255) & ~(size_t)255;
    int* gstart = (int*)(w + off); off += NLVL * 9 * 4;
    int* gcnt   = (int*)(w + off); off += NLVL * 8 * 4;
    int* ctr    = (int*)(w + off); off += NLVL * 8 * 4;
    const size_t zero_ints = NLVL * 9 + NLVL * 8 + NLVL * 8;
    off = (off + 255) & ~(size_t)255;
    float* Ccomp = (float*)(w + off); off += (size_t)8 * D * D * 4;
    float* dcomp = (float*)(w + off); off += 8 * D * 4;
    float* sv    = (float*)(w + off); off += D * 4;
    float* s0    = (float*)(w + off); off += 256;
    off = (off + 255) & ~(size_t)255;
    unsigned short* ewt = (unsigned short*)(w + off); off += (size_t)8 * D * D * 2;
    unsigned short* cwt = (unsigned short*)(w + off); off += (size_t)8 * D * D * 2;
    unsigned short* dwt = (unsigned short*)(w + off); off += (size_t)D * D * 2;

    hipMemsetAsync(perm, 0xFF, (size_t)PERM_TOTAL * 4, stream);
    hipMemsetAsync(gstart, 0, zero_ints * 4, stream);

    count_kernel<<<128, 256, 0, stream>>>(edges, gcnt, Nn);
    prefix_sv_kernel<<<1, 256, 0, stream>>>(gcnt, gstart, data_W, data_b, score_W, sv, s0);
    place_kernel<<<(Nn - 1 + CHUNK - 1) / CHUNK, 256, 0, stream>>>(edges, gstart, ctr, perm, Nn);
    compose_kernel<<<32, 256, 0, stream>>>(data_W, data_b, edge_W, edge_b, Ccomp, dcomp);
    convert_kernel<<<17, 256, 0, stream>>>(edge_W, Ccomp, data_W, ewt, cwt, dwt);

    // merged leaf GEMM (level 16) + embed, one launch
    {
        const int embed_blks = (NI + TS - 1) / TS;
        const int lbase_leaf = ((2 << 16) - 2) + LVLPAD * 16;
        leaf_embed_kernel<<<LEAF_BLKS + embed_blks, 256, 0, stream>>>(
            X, data_vecs, data, perm, gstart + 16 * 9,
            cwt, dcomp, sv, s0, dwt, data_b, out, NI, lbase_leaf);
    }

    // big internal levels 15..11 (MFMA, edge-sorted tiles)
    for (int l = 15; l >= 11; l--) {
        const int M = 2 << l;
        const int lbase = ((2 << l) - 2) + LVLPAD * l;
        tree_gemm_kernel<<<M / TS + 8, 256, 0, stream>>>(
            X, perm, gstart + l * 9, ewt, edge_b, score_W, out, lbase);
    }

    // top of tree: subtree-owned blocks, no grid barriers
    sub_kernel<<<256, 256, 0, stream>>>(X, edge_W, edge_b, edges, score_W, out, 255, 4); // depths 11..8
    sub_kernel<<<16, 256, 0, stream>>>(X, edge_W, edge_b, edges, score_W, out, 15, 4);   // depths 7..4
    sub_kernel<<<1, 256, 0, stream>>>(X, edge_W, edge_b, edges, score_W, out, 0, 4);     // depths 3..1 + root
}

// Round 7
// 339.673 us; speedup vs baseline: 1.3161x; 1.0210x over previous
//
#include <hip/hip_runtime.h>

#define D 128
#define NLVL 17          // parent levels 0..16
#define TS 128           // rows per big GEMM tile
#define LVLPAD 1024      // per-level perm slack for group padding
#define LDSTR 136        // LDS row stride in bf16 elems (272B: conflict-free b128)
#define LEAF_BLKS 1032   // ceil((131072 + 8*127)/128)

typedef float  floatx4 __attribute__((ext_vector_type(4)));
typedef short  shortx8 __attribute__((ext_vector_type(8)));

__device__ __forceinline__ unsigned short f2bf(float f) {   // RNE fp32->bf16
    unsigned u = __float_as_uint(f);
    u += 0x7FFFu + ((u >> 16) & 1u);
    return (unsigned short)(u >> 16);
}
__device__ __forceinline__ float bf2f(unsigned short h) {
    return __uint_as_float(((unsigned)h) << 16);
}
__device__ __forceinline__ int lvl_base_dev(int l) { return ((2 << l) - 2) + LVLPAD * l; }

// ============ sort step 1: per-(level,edge) counts (levels >= 11) ============
__global__ __launch_bounds__(256) void count_kernel(
    const int* __restrict__ edges, int* __restrict__ gcnt, int Nn)
{
    __shared__ int lc[NLVL * 8];
    const int t = threadIdx.x;
    for (int i = t; i < NLVL * 8; i += 256) lc[i] = 0;
    __syncthreads();
    for (int c = 1 + blockIdx.x * 256 + t; c < Nn; c += gridDim.x * 256) {
        const int e = edges[c];
        const int p = (c - 1) >> 1;
        const int l = 31 - __clz(p + 1);
        if (l >= 11) atomicAdd(&lc[l * 8 + e], 1);
    }
    __syncthreads();
    for (int i = t; i < NLVL * 8; i += 256) if (lc[i]) atomicAdd(&gcnt[i], lc[i]);
}

// ============ sort step 2: padded prefix (+ sv = data_W @ score_W, s0 = data_b . score_W) ============
__global__ __launch_bounds__(256) void prefix_sv_kernel(
    const int* __restrict__ gcnt, int* __restrict__ gstart,
    const float* __restrict__ dW, const float* __restrict__ db,
    const float* __restrict__ sWs, float* __restrict__ sv, float* __restrict__ s0)
{
    __shared__ float red[256];
    const int t = threadIdx.x;
    if (t < D) {
        float acc = 0.f;
        for (int j = 0; j < D; j++) acc += dW[t * D + j] * sWs[j];
        sv[t] = acc;
    }
    red[t] = (t < D) ? db[t] * sWs[t] : 0.f;
    __syncthreads();
    for (int s = 128; s > 0; s >>= 1) { if (t < s) red[t] += red[t + s]; __syncthreads(); }
    if (t == 0) {
        *s0 = red[0];
        for (int l = 0; l < NLVL; l++) {
            int acc = 0;
            for (int e = 0; e < 8; e++) {
                gstart[l * 9 + e] = acc;
                if (l >= 11) acc = (acc + gcnt[l * 8 + e] + (TS - 1)) & ~(TS - 1);
            }
            gstart[l * 9 + 8] = acc;
        }
    }
}

// ============ sort step 3: placement (levels >= 11 only) ============
#define CHUNK 2048
__global__ __launch_bounds__(256) void place_kernel(
    const int* __restrict__ edges, const int* __restrict__ gstart,
    int* __restrict__ ctr, int* __restrict__ perm, int Nn)
{
    __shared__ unsigned char key_s[CHUNK];
    __shared__ int lcnt[NLVL * 8], lbase[NLVL * 8];
    __shared__ int gs_s[NLVL * 9];
    const int t = threadIdx.x;
    for (int i = t; i < NLVL * 8; i += 256) lcnt[i] = 0;
    for (int i = t; i < NLVL * 9; i += 256) gs_s[i] = gstart[i];
    const int base = 1 + blockIdx.x * CHUNK;
    __syncthreads();
    for (int i = t; i < CHUNK; i += 256) {
        const int c = base + i;
        if (c < Nn) {
            const int e = edges[c];
            const int p = (c - 1) >> 1;
            const int l = 31 - __clz(p + 1);
            if (l >= 11) {
                const int k = l * 8 + e;
                key_s[i] = (unsigned char)k;
                atomicAdd(&lcnt[k], 1);
            } else key_s[i] = 255;
        } else key_s[i] = 255;
    }
    __syncthreads();
    for (int i = t; i < NLVL * 8; i += 256) {
        const int n = lcnt[i];
        lbase[i] = n ? atomicAdd(&ctr[i], n) : 0;
        lcnt[i] = 0;
    }
    __syncthreads();
    for (int i = t; i < CHUNK; i += 256) {
        const int c = base + i;
        if (c >= Nn) continue;
        const int k = key_s[i];
        if (k == 255) continue;
        const int off = atomicAdd(&lcnt[k], 1);
        const int l = k >> 3, e = k & 7;
        const int pos = gs_s[l * 9 + e] + lbase[k] + off;
        perm[lvl_base_dev(l) + pos] = c;
    }
}

// ============ vecs fp32 -> bf16 ============
__global__ __launch_bounds__(256) void vec2bf_kernel(
    const float* __restrict__ vecs, unsigned short* __restrict__ vbf, int n4)
{
    for (int i = blockIdx.x * 256 + threadIdx.x; i < n4; i += gridDim.x * 256) {
        const float4 v = ((const float4*)vecs)[i];
        uint2 o;
        o.x = (unsigned)f2bf(v.x) | ((unsigned)f2bf(v.y) << 16);
        o.y = (unsigned)f2bf(v.z) | ((unsigned)f2bf(v.w) << 16);
        ((uint2*)vbf)[i] = o;
    }
}

// ============ compose: Ccomp_e = data_W @ edge_W[e] (fp32), dcomp_e = data_b @ edge_W[e] + edge_b[e] ============
__global__ __launch_bounds__(256) void compose_kernel(
    const float* __restrict__ dW, const float* __restrict__ db,
    const float* __restrict__ eW, const float* __restrict__ eb,
    float* __restrict__ C, float* __restrict__ dv)
{
    __shared__ float aw_s[D * D];
    __shared__ float w_s[D * 32];
    const int t = threadIdx.x;
    const int e = blockIdx.x >> 2, cc = blockIdx.x & 3;
    for (int i = t; i < D * D / 4; i += 256) ((float4*)aw_s)[i] = ((const float4*)dW)[i];
    for (int i = t; i < D * 8; i += 256) {
        const int k = i >> 3, j4 = i & 7;
        ((float4*)w_s)[i] = ((const float4*)eW)[((size_t)e * D + k) * 32 + cc * 8 + j4];
    }
    __syncthreads();
    const int r2 = t >> 1, h = t & 1;
    float4 acc[4];
    #pragma unroll
    for (int m = 0; m < 4; m++) acc[m] = make_float4(0.f, 0.f, 0.f, 0.f);
    for (int k = 0; k < D; k++) {
        const float a = aw_s[r2 * D + k];
        #pragma unroll
        for (int m = 0; m < 4; m++) {
            const float4 w4 = ((const float4*)w_s)[k * 8 + h * 4 + m];
            acc[m].x += a * w4.x; acc[m].y += a * w4.y; acc[m].z += a * w4.z; acc[m].w += a * w4.w;
        }
    }
    #pragma unroll
    for (int m = 0; m < 4; m++)
        ((float4*)C)[((size_t)e * D + r2) * 32 + cc * 8 + h * 4 + m] = acc[m];
    if (t < 32) {
        float a2 = 0.f;
        for (int k = 0; k < D; k++) a2 += db[k] * w_s[k * 32 + t];
        dv[e * D + cc * 32 + t] = a2 + eb[e * D + cc * 32 + t];
    }
}

// ============ convert+transpose weights to bf16 [n][k] ============
__global__ __launch_bounds__(256) void convert_kernel(
    const float* __restrict__ eW, const float* __restrict__ Ccomp,
    const float* __restrict__ dW,
    unsigned short* __restrict__ ewt, unsigned short* __restrict__ cwt,
    unsigned short* __restrict__ dwt)
{
    __shared__ float lds[D * 129];
    const int b = blockIdx.x;
    const float* src = (b < 8) ? (eW + (size_t)b * D * D)
                     : (b < 16) ? (Ccomp + (size_t)(b - 8) * D * D)
                     : dW;
    unsigned short* dst = (b < 8) ? (ewt + (size_t)b * D * D)
                        : (b < 16) ? (cwt + (size_t)(b - 8) * D * D)
                        : dwt;
    const int t = threadIdx.x;
    for (int i = t; i < D * D / 4; i += 256) {
        float4 v = ((const float4*)src)[i];
        const int k = (i * 4) >> 7, n = (i * 4) & 127;
        lds[k * 129 + n]     = v.x;
        lds[k * 129 + n + 1] = v.y;
        lds[k * 129 + n + 2] = v.z;
        lds[k * 129 + n + 3] = v.w;
    }
    __syncthreads();
    const int n = t >> 1, h = t & 1;
    for (int k = 0; k < 64; k++)
        dst[(size_t)n * D + h * 64 + k] = f2bf(lds[(h * 64 + k) * 129 + n]);
}

// ============ merged leaf GEMM + embed (bf16 gather, W direct from global, 35KB LDS) ============
// leaf blocks: rows = vbf[data[perm[c]]], W=cwt[e], bias=dcomp[e], score = row.sv + s0
// embed blocks: rows = vbf[data[node]], W=dwt, bias=db, no score
__global__ __launch_bounds__(256, 4) void leaf_embed_kernel(
    unsigned short* __restrict__ X,
    const unsigned short* __restrict__ vbf,
    const int* __restrict__ data,
    const int* __restrict__ perm,
    const int* __restrict__ gstart9,
    const unsigned short* __restrict__ cwt,
    const float* __restrict__ dcomp,
    const float* __restrict__ sv, const float* __restrict__ s0p,
    const unsigned short* __restrict__ dwt,
    const float* __restrict__ db,
    float* __restrict__ out,
    int NI, int lbase_leaf)
{
    __shared__ unsigned short a_s[TS * LDSTR];   // ~34.8 KB total
    const int t = threadIdx.x;
    const bool is_leaf = (blockIdx.x < LEAF_BLKS);
    const int r = t >> 1, h = t & 1;

    int e = 0, c;
    const unsigned short* Wg;
    const float* bias;
    if (is_leaf) {
        const int ts = blockIdx.x * TS;
        if (ts >= gstart9[8]) return;
        #pragma unroll
        for (int j = 1; j < 8; j++) if (ts >= gstart9[j]) e = j;
        c = perm[lbase_leaf + ts + r];
        Wg = cwt + (size_t)e * D * D;
        bias = dcomp + (size_t)e * D;
    } else {
        const int node = (blockIdx.x - LEAF_BLKS) * TS + r;
        c = (node < NI) ? node : -1;
        Wg = dwt;
        bias = db;
    }

    {   // stage A (bf16 gather) + fused leaf score
        unsigned short* dst = a_s + r * LDSTR + h * 64;
        if (c >= 0) {
            const uint4* src = (const uint4*)(vbf + (size_t)data[c] * D + h * 64);
            if (is_leaf) {
                float sc = 0.f;
                #pragma unroll
                for (int j = 0; j < 8; j++) {
                    const uint4 v = src[j];
                    const unsigned* pv = (const unsigned*)&v;
                    #pragma unroll
                    for (int u = 0; u < 4; u++) {
                        const int n = h * 64 + j * 8 + u * 2;
                        sc += bf2f((unsigned short)pv[u]) * sv[n]
                            + bf2f((unsigned short)(pv[u] >> 16)) * sv[n + 1];
                    }
                    ((uint4*)dst)[j] = v;
                }
                sc += __shfl_xor(sc, 1, 64);
                if (h == 0) out[c] = sc + s0p[0];
            } else {
                #pragma unroll
                for (int j = 0; j < 8; j++) ((uint4*)dst)[j] = src[j];
            }
        } else {
            #pragma unroll
            for (int j = 0; j < 8; j++) ((uint4*)dst)[j] = make_uint4(0u, 0u, 0u, 0u);
        }
    }
    __syncthreads();

    const int lane = t & 63, wv = t >> 6;
    const int cq = lane & 15, q = lane >> 4;
    const floatx4 z4 = {0.f, 0.f, 0.f, 0.f};
    floatx4 acc[8][2];
    #pragma unroll
    for (int i = 0; i < 8; i++) { acc[i][0] = z4; acc[i][1] = z4; }
    #pragma unroll
    for (int ks = 0; ks < 4; ks++) {
        shortx8 bfr[2];
        #pragma unroll
        for (int nl = 0; nl < 2; nl++) {
            const int n = (wv * 2 + nl) * 16 + cq;
            bfr[nl] = *(const shortx8*)(Wg + (size_t)n * D + ks * 32 + q * 8);
        }
        #pragma unroll
        for (int mt = 0; mt < 8; mt++) {
            const shortx8 af = *(const shortx8*)(a_s + (mt * 16 + cq) * LDSTR + ks * 32 + q * 8);
            acc[mt][0] = __builtin_amdgcn_mfma_f32_16x16x32_bf16(af, bfr[0], acc[mt][0], 0, 0, 0);
            acc[mt][1] = __builtin_amdgcn_mfma_f32_16x16x32_bf16(af, bfr[1], acc[mt][1], 0, 0, 0);
        }
    }
    __syncthreads();
    #pragma unroll
    for (int nl = 0; nl < 2; nl++) {
        const int n = (wv * 2 + nl) * 16 + cq;
        const float bn = bias[n];
        #pragma unroll
        for (int mt = 0; mt < 8; mt++) {
            #pragma unroll
            for (int rg = 0; rg < 4; rg++) {
                const int m = mt * 16 + q * 4 + rg;
                a_s[m * LDSTR + n] = f2bf(acc[mt][nl][rg] + bn);
            }
        }
    }
    __syncthreads();
    if (c >= 0) {
        uint4* dst = (uint4*)(X + (size_t)c * D + h * 64);
        const uint4* srcl = (const uint4*)(a_s + r * LDSTR + h * 64);
        #pragma unroll
        for (int j = 0; j < 8; j++) dst[j] = srcl[j];
    }
}

// ============ big tree GEMM (levels 15..11): combine+score+ReLU staged, W direct ============
__global__ __launch_bounds__(256, 4) void tree_gemm_kernel(
    unsigned short* __restrict__ X,
    const int* __restrict__ perm,
    const int* __restrict__ gstart9,
    const unsigned short* __restrict__ ewt,
    const float* __restrict__ eb,
    const float* __restrict__ svec,
    float* __restrict__ out,
    int lbase)
{
    __shared__ unsigned short a_s[TS * LDSTR];
    const int t = threadIdx.x;
    const int ts = blockIdx.x * TS;
    if (ts >= gstart9[8]) return;
    int e = 0;
    #pragma unroll
    for (int j = 1; j < 8; j++) if (ts >= gstart9[j]) e = j;
    const int r = t >> 1, h = t & 1;
    const int c = perm[lbase + ts + r];
    const unsigned short* Wg = ewt + (size_t)e * D * D;

    {   // stage A: fused combine + score + ReLU
        unsigned short* dst = a_s + r * LDSTR + h * 64;
        if (c >= 0) {
            const uint4* xr = (const uint4*)(X + (size_t)c * D + h * 64);
            const uint4* ya = (const uint4*)(X + (size_t)(2 * c + 1) * D + h * 64);
            const uint4* yb = (const uint4*)(X + (size_t)(2 * c + 2) * D + h * 64);
            const float inv3 = 1.0f / 3.0f;
            float sc = 0.f;
            #pragma unroll
            for (int j = 0; j < 8; j++) {
                uint4 ra = xr[j], rb = ya[j], rc = yb[j];
                const unsigned* pa = (const unsigned*)&ra;
                const unsigned* pb = (const unsigned*)&rb;
                const unsigned* pc = (const unsigned*)&rc;
                unsigned ou[4];
                #pragma unroll
                for (int u = 0; u < 4; u++) {
                    const float h0 = (bf2f((unsigned short)pa[u]) + bf2f((unsigned short)pb[u])
                                    + bf2f((unsigned short)pc[u])) * inv3;
                    const float h1 = (bf2f((unsigned short)(pa[u] >> 16)) + bf2f((unsigned short)(pb[u] >> 16))
                                    + bf2f((unsigned short)(pc[u] >> 16))) * inv3;
                    const int n = h * 64 + j * 8 + u * 2;
                    sc += h0 * svec[n] + h1 * svec[n + 1];
                    unsigned short q0 = f2bf(h0), q1 = f2bf(h1);
                    q0 = (q0 & 0x8000u) ? 0 : q0;
                    q1 = (q1 & 0x8000u) ? 0 : q1;
                    ou[u] = (unsigned)q0 | ((unsigned)q1 << 16);
                }
                ((uint4*)dst)[j] = make_uint4(ou[0], ou[1], ou[2], ou[3]);
            }
            sc += __shfl_xor(sc, 1, 64);
            if (h == 0) out[c] = sc;
        } else {
            #pragma unroll
            for (int j = 0; j < 8; j++) ((uint4*)dst)[j] = make_uint4(0u, 0u, 0u, 0u);
        }
    }
    __syncthreads();
    const int lane = t & 63, wv = t >> 6;
    const int cq = lane & 15, q = lane >> 4;
    const floatx4 z4 = {0.f, 0.f, 0.f, 0.f};
    floatx4 acc[8][2];
    #pragma unroll
    for (int i = 0; i < 8; i++) { acc[i][0] = z4; acc[i][1] = z4; }
    #pragma unroll
    for (int ks = 0; ks < 4; ks++) {
        shortx8 bfr[2];
        #pragma unroll
        for (int nl = 0; nl < 2; nl++) {
            const int n = (wv * 2 + nl) * 16 + cq;
            bfr[nl] = *(const shortx8*)(Wg + (size_t)n * D + ks * 32 + q * 8);
        }
        #pragma unroll
        for (int mt = 0; mt < 8; mt++) {
            const shortx8 af = *(const shortx8*)(a_s + (mt * 16 + cq) * LDSTR + ks * 32 + q * 8);
            acc[mt][0] = __builtin_amdgcn_mfma_f32_16x16x32_bf16(af, bfr[0], acc[mt][0], 0, 0, 0);
            acc[mt][1] = __builtin_amdgcn_mfma_f32_16x16x32_bf16(af, bfr[1], acc[mt][1], 0, 0, 0);
        }
    }
    __syncthreads();
    #pragma unroll
    for (int nl = 0; nl < 2; nl++) {
        const int n = (wv * 2 + nl) * 16 + cq;
        const float bn = eb[(size_t)e * D + n];
        #pragma unroll
        for (int mt = 0; mt < 8; mt++) {
            #pragma unroll
            for (int rg = 0; rg < 4; rg++) {
                const int m = mt * 16 + q * 4 + rg;
                a_s[m * LDSTR + n] = f2bf(acc[mt][nl][rg] + bn);
            }
        }
    }
    __syncthreads();
    if (c >= 0) {
        uint4* dst = (uint4*)(X + (size_t)c * D + h * 64);
        const uint4* srcl = (const uint4*)(a_s + r * LDSTR + h * 64);
        #pragma unroll
        for (int j = 0; j < 8; j++) dst[j] = srcl[j];
    }
}

// ============ subtree kernel (top levels): block owns subtree, __syncthreads between depths ============
__global__ __launch_bounds__(256) void sub_kernel(
    unsigned short* __restrict__ X,
    const float* __restrict__ eW,
    const float* __restrict__ eb,
    const int* __restrict__ edges,
    const float* __restrict__ sW,
    float* __restrict__ out,
    int rbase, int nlev)
{
    __shared__ __align__(16) float xbuf[4][D];
    const int t = threadIdx.x, wv = t >> 6, lane = t & 63;
    const int u = rbase + blockIdx.x;
    const int j2 = lane * 2;
    const float inv3 = 1.0f / 3.0f;

    for (int lev = nlev - 1; lev >= 0; lev--) {
        const int first = ((u + 1) << lev) - 1;
        const int cnt = 1 << lev;
        for (int i = wv; i < cnt; i += 4) {
            const int n = first + i;
            const unsigned ra = *(const unsigned*)(X + (size_t)n * D + j2);
            const unsigned rb = *(const unsigned*)(X + (size_t)(2 * n + 1) * D + j2);
            const unsigned rc = *(const unsigned*)(X + (size_t)(2 * n + 2) * D + j2);
            const float h0 = (bf2f((unsigned short)ra) + bf2f((unsigned short)rb)
                            + bf2f((unsigned short)rc)) * inv3;
            const float h1 = (bf2f((unsigned short)(ra >> 16)) + bf2f((unsigned short)(rb >> 16))
                            + bf2f((unsigned short)(rc >> 16))) * inv3;
            float sc = h0 * sW[j2] + h1 * sW[j2 + 1];
            #pragma unroll
            for (int o = 32; o > 0; o >>= 1) sc += __shfl_xor(sc, o, 64);
            if (lane == 0) out[n] = sc;
            if (n == 0) continue;
            float2 x2 = make_float2(fmaxf(h0, 0.f), fmaxf(h1, 0.f));
            *(float2*)(xbuf[wv] + j2) = x2;
            const int e = edges[n];
            const float* W = eW + (size_t)e * D * D;
            float y0 = 0.f, y1 = 0.f;
            #pragma unroll 8
            for (int k4 = 0; k4 < 32; k4++) {
                const float4 xk = *(const float4*)(xbuf[wv] + k4 * 4);
                const float2 w0 = *(const float2*)(W + (size_t)(k4 * 4 + 0) * D + j2);
                const float2 w1 = *(const float2*)(W + (size_t)(k4 * 4 + 1) * D + j2);
                const float2 w2 = *(const float2*)(W + (size_t)(k4 * 4 + 2) * D + j2);
                const float2 w3 = *(const float2*)(W + (size_t)(k4 * 4 + 3) * D + j2);
                y0 += xk.x * w0.x + xk.y * w1.x + xk.z * w2.x + xk.w * w3.x;
                y1 += xk.x * w0.y + xk.y * w1.y + xk.z * w2.y + xk.w * w3.y;
            }
            y0 += eb[e * D + j2];
            y1 += eb[e * D + j2 + 1];
            const unsigned o = (unsigned)f2bf(y0) | ((unsigned)f2bf(y1) << 16);
            *(unsigned*)(X + (size_t)n * D + j2) = o;
        }
        __syncthreads();
    }
}

extern "C" void kernel_launch(void* const* d_in, const int* in_sizes, int n_in,
                              void* d_out, int out_size, void* d_ws, size_t ws_size,
                              hipStream_t stream) {
    const int*   data      = (const int*)d_in[0];
    const int*   edges     = (const int*)d_in[1];
    const float* data_vecs = (const float*)d_in[2];
    const float* data_W    = (const float*)d_in[3];
    const float* data_b    = (const float*)d_in[4];
    const float* edge_W    = (const float*)d_in[5];
    const float* edge_b    = (const float*)d_in[6];
    const float* score_W   = (const float*)d_in[7];
    float* out = (float*)d_out;

    const int Nn = in_sizes[0];          // 2^18 - 1
    const int NI = Nn >> 1;              // internal nodes: 2^17 - 1
    const int VD = in_sizes[2];          // V * D
    const int PERM_TOTAL = (Nn - 1) + LVLPAD * NLVL;

    char* w = (char*)d_ws;
    size_t off = 0;
    unsigned short* X = (unsigned short*)(w + off); off += (size_t)Nn * D * 2;
    int* perm = (int*)(w + off);  off += (size_t)PERM_TOTAL * 4;
    off = (off + 255) & ~(size_t)255;
    int* gstart = (int*)(w + off); off += NLVL * 9 * 4;
    int* gcnt   = (int*)(w + off); off += NLVL * 8 * 4;
    int* ctr    = (int*)(w + off); off += NLVL * 8 * 4;
    const size_t zero_ints = NLVL * 9 + NLVL * 8 + NLVL * 8;
    off = (off + 255) & ~(size_t)255;
    float* Ccomp = (float*)(w + off); off += (size_t)8 * D * D * 4;
    float* dcomp = (float*)(w + off); off += 8 * D * 4;
    float* sv    = (float*)(w + off); off += D * 4;
    float* s0    = (float*)(w + off); off += 256;
    off = (off + 255) & ~(size_t)255;
    unsigned short* ewt = (unsigned short*)(w + off); off += (size_t)8 * D * D * 2;
    unsigned short* cwt = (unsigned short*)(w + off); off += (size_t)8 * D * D * 2;
    unsigned short* dwt = (unsigned short*)(w + off); off += (size_t)D * D * 2;
    off = (off + 255) & ~(size_t)255;
    unsigned short* vbf = (unsigned short*)(w + off); off += (size_t)VD * 2;

    hipMemsetAsync(perm, 0xFF, (size_t)PERM_TOTAL * 4, stream);
    hipMemsetAsync(gstart, 0, zero_ints * 4, stream);

    count_kernel<<<128, 256, 0, stream>>>(edges, gcnt, Nn);
    prefix_sv_kernel<<<1, 256, 0, stream>>>(gcnt, gstart, data_W, data_b, score_W, sv, s0);
    place_kernel<<<(Nn - 1 + CHUNK - 1) / CHUNK, 256, 0, stream>>>(edges, gstart, ctr, perm, Nn);
    compose_kernel<<<32, 256, 0, stream>>>(data_W, data_b, edge_W, edge_b, Ccomp, dcomp);
    convert_kernel<<<17, 256, 0, stream>>>(edge_W, Ccomp, data_W, ewt, cwt, dwt);
    vec2bf_kernel<<<1024, 256, 0, stream>>>(data_vecs, vbf, VD / 4);

    // merged leaf GEMM (level 16) + embed, one launch
    {
        const int embed_blks = (NI + TS - 1) / TS;
        const int lbase_leaf = ((2 << 16) - 2) + LVLPAD * 16;
        leaf_embed_kernel<<<LEAF_BLKS + embed_blks, 256, 0, stream>>>(
            X, vbf, data, perm, gstart + 16 * 9,
            cwt, dcomp, sv, s0, dwt, data_b, out, NI, lbase_leaf);
    }

    // big internal levels 15..11 (MFMA, edge-sorted tiles)
    for (int l = 15; l >= 11; l--) {
        const int M = 2 << l;
        const int lbase = ((2 << l) - 2) + LVLPAD * l;
        tree_gemm_kernel<<<M / TS + 8, 256, 0, stream>>>(
            X, perm, gstart + l * 9, ewt, edge_b, score_W, out, lbase);
    }

    // top of tree: subtree-owned blocks, no grid barriers
    sub_kernel<<<256, 256, 0, stream>>>(X, edge_W, edge_b, edges, score_W, out, 255, 4); // depths 11..8
    sub_kernel<<<16, 256, 0, stream>>>(X, edge_W, edge_b, edges, score_W, out, 15, 4);   // depths 7..4
    sub_kernel<<<1, 256, 0, stream>>>(X, edge_W, edge_b, edges, score_W, out, 0, 4);     // depths 3..1 + root
}

// Round 8
// 339.373 us; speedup vs baseline: 1.3173x; 1.0009x over previous
//
#include <hip/hip_runtime.h>

#define D 128
#define NLVL 17          // parent levels 0..16
#define TS 128           // rows per big GEMM tile
#define LVLPAD 1024      // per-level perm slack for group padding
#define LDSTR 136        // LDS row stride in bf16 elems (272B: conflict-free b128)
#define LEAF_BLKS 1032   // ceil((131072 + 8*127)/128)
#define CHUNK 2048

typedef float  floatx4 __attribute__((ext_vector_type(4)));
typedef short  shortx8 __attribute__((ext_vector_type(8)));

__device__ __forceinline__ unsigned short f2bf(float f) {   // RNE fp32->bf16
    unsigned u = __float_as_uint(f);
    u += 0x7FFFu + ((u >> 16) & 1u);
    return (unsigned short)(u >> 16);
}
__device__ __forceinline__ float bf2f(unsigned short h) {
    return __uint_as_float(((unsigned)h) << 16);
}
__device__ __forceinline__ int lvl_base_dev(int l) { return ((2 << l) - 2) + LVLPAD * l; }

// ============ sort 1: per-(level,edge) counts, levels 13..16 only ============
// Block b STORES its 32 counters to gcnt128[b*32..] — no global pre-zero needed.
__global__ __launch_bounds__(256) void count_kernel(
    const int* __restrict__ edges, int* __restrict__ gcnt128, int Nn)
{
    __shared__ int lc[32];
    const int t = threadIdx.x;
    if (t < 32) lc[t] = 0;
    __syncthreads();
    for (int c = 16383 + blockIdx.x * 256 + t; c < Nn; c += gridDim.x * 256) {
        const int e = edges[c];
        const int p = (c - 1) >> 1;
        const int l = 31 - __clz(p + 1);      // 13..16
        atomicAdd(&lc[(l - 13) * 8 + e], 1);
    }
    __syncthreads();
    if (t < 32) gcnt128[blockIdx.x * 32 + t] = lc[t];
}

// ============ sort 2: reduce counts, padded prefix, zero ctr ============
__global__ __launch_bounds__(256) void prefix_kernel(
    const int* __restrict__ gcnt128, int* __restrict__ gstart,
    int* __restrict__ glim, int* __restrict__ ctr)
{
    __shared__ int part[256];
    __shared__ int tot[32];
    const int t = threadIdx.x;
    const int k = t & 31, bs = t >> 5;
    int s = 0;
    for (int b = bs; b < 128; b += 8) s += gcnt128[b * 32 + k];
    part[t] = s;
    __syncthreads();
    if (t < 32) {
        int tt = 0;
        #pragma unroll
        for (int i = 0; i < 8; i++) tt += part[t + 32 * i];
        tot[t] = tt;
        ctr[t] = 0;
    }
    __syncthreads();
    if (t == 0) {
        for (int li = 0; li < 4; li++) {
            const int l = 13 + li;
            int acc = 0;
            for (int e = 0; e < 8; e++) {
                gstart[l * 9 + e] = acc;
                glim[l * 8 + e] = acc + tot[li * 8 + e];
                acc = (acc + tot[li * 8 + e] + (TS - 1)) & ~(TS - 1);
            }
            gstart[l * 9 + 8] = acc;
        }
    }
}

// ============ sort 3: placement (levels 13..16) ============
__global__ __launch_bounds__(256) void place_kernel(
    const int* __restrict__ edges, const int* __restrict__ gstart,
    int* __restrict__ ctr, int* __restrict__ perm, int Nn)
{
    __shared__ unsigned char key_s[CHUNK];
    __shared__ int lcnt[32], lbase[32];
    __shared__ int gs_s[4 * 9];
    const int t = threadIdx.x;
    if (t < 32) lcnt[t] = 0;
    if (t < 36) gs_s[t] = gstart[13 * 9 + t];
    const int base = 16383 + blockIdx.x * CHUNK;
    __syncthreads();
    for (int i = t; i < CHUNK; i += 256) {
        const int c = base + i;
        if (c < Nn) {
            const int e = edges[c];
            const int p = (c - 1) >> 1;
            const int l = 31 - __clz(p + 1);
            const int kk = (l - 13) * 8 + e;
            key_s[i] = (unsigned char)kk;
            atomicAdd(&lcnt[kk], 1);
        } else key_s[i] = 255;
    }
    __syncthreads();
    if (t < 32) {
        const int n = lcnt[t];
        lbase[t] = n ? atomicAdd(&ctr[t], n) : 0;
        lcnt[t] = 0;
    }
    __syncthreads();
    for (int i = t; i < CHUNK; i += 256) {
        const int c = base + i;
        if (c >= Nn) continue;
        const int kk = key_s[i];
        if (kk == 255) continue;
        const int off = atomicAdd(&lcnt[kk], 1);
        const int l = (kk >> 3) + 13, e = kk & 7;
        const int pos = gs_s[(l - 13) * 9 + e] + lbase[kk] + off;
        perm[lvl_base_dev(l) + pos] = c;
    }
}

// ============ prep (fused): compose->cwt+dcomp | ewt/dwt transpose | sv/s0 | vec2bf ============
__global__ __launch_bounds__(256) void prep_kernel(
    const float* __restrict__ dW, const float* __restrict__ db,
    const float* __restrict__ eW, const float* __restrict__ eb,
    const float* __restrict__ sWs, const float* __restrict__ vecs,
    unsigned short* __restrict__ ewt, unsigned short* __restrict__ cwt,
    unsigned short* __restrict__ dwt, float* __restrict__ dcomp,
    float* __restrict__ sv, float* __restrict__ s0,
    unsigned short* __restrict__ vbf, int n4)
{
    __shared__ float smem[8448];
    const int b = blockIdx.x, t = threadIdx.x;
    if (b < 32) {
        // ---- compose block: C_e[:, cc*32..] = dW @ eW_e, emit cwt (bf16 [n][k]) + dcomp ----
        float* w_s = smem;          // [k][32] slice of eW_e
        float* cs  = smem + 4096;   // [k][33] C block (padded)
        const int e = b >> 2, cc = b & 3;
        for (int i = t; i < D * 8; i += 256) {
            const int k = i >> 3, j4 = i & 7;
            ((float4*)w_s)[i] = ((const float4*)eW)[((size_t)e * D + k) * 32 + cc * 8 + j4];
        }
        __syncthreads();
        const int r2 = t >> 1, h = t & 1;   // C row r2, 16-col half h
        float4 acc[4];
        #pragma unroll
        for (int m = 0; m < 4; m++) acc[m] = make_float4(0.f, 0.f, 0.f, 0.f);
        for (int k = 0; k < D; k++) {
            const float a = dW[(size_t)r2 * D + k];
            #pragma unroll
            for (int m = 0; m < 4; m++) {
                const float4 w4 = ((const float4*)w_s)[k * 8 + h * 4 + m];
                acc[m].x += a * w4.x; acc[m].y += a * w4.y; acc[m].z += a * w4.z; acc[m].w += a * w4.w;
            }
        }
        #pragma unroll
        for (int m = 0; m < 4; m++) {
            cs[r2 * 33 + h * 16 + m * 4 + 0] = acc[m].x;
            cs[r2 * 33 + h * 16 + m * 4 + 1] = acc[m].y;
            cs[r2 * 33 + h * 16 + m * 4 + 2] = acc[m].z;
            cs[r2 * 33 + h * 16 + m * 4 + 3] = acc[m].w;
        }
        __syncthreads();
        {   // transpose out: cwt[e][n][k]
            const int nn = t >> 3, kseg = t & 7, k0 = kseg * 16;
            unsigned ow[8];
            #pragma unroll
            for (int i2 = 0; i2 < 8; i2++) {
                const unsigned short lo = f2bf(cs[(k0 + 2 * i2) * 33 + nn]);
                const unsigned short hi = f2bf(cs[(k0 + 2 * i2 + 1) * 33 + nn]);
                ow[i2] = (unsigned)lo | ((unsigned)hi << 16);
            }
            uint4* dstp = (uint4*)(cwt + (size_t)e * D * D + (size_t)(cc * 32 + nn) * D + k0);
            dstp[0] = make_uint4(ow[0], ow[1], ow[2], ow[3]);
            dstp[1] = make_uint4(ow[4], ow[5], ow[6], ow[7]);
        }
        if (t < 32) {   // dcomp
            float a2 = 0.f;
            for (int k = 0; k < D; k++) a2 += db[k] * w_s[k * 32 + t];
            dcomp[e * D + cc * 32 + t] = a2 + eb[e * D + cc * 32 + t];
        }
    } else if (b < 41) {
        // ---- transpose to bf16 [n][k]: b-32<8 -> ewt[e], b==40 -> dwt ----
        float* lds = smem;   // 64 x 129
        const int bb = b - 32;
        const float* src = (bb < 8) ? (eW + (size_t)bb * D * D) : dW;
        unsigned short* dst = (bb < 8) ? (ewt + (size_t)bb * D * D) : dwt;
        for (int half = 0; half < 2; half++) {
            __syncthreads();
            for (int i = t; i < 64 * D / 4; i += 256) {
                float4 v = ((const float4*)src)[half * (64 * D / 4) + i];
                const int k = (i * 4) >> 7, n = (i * 4) & 127;
                lds[k * 129 + n]     = v.x;
                lds[k * 129 + n + 1] = v.y;
                lds[k * 129 + n + 2] = v.z;
                lds[k * 129 + n + 3] = v.w;
            }
            __syncthreads();
            const int n = t >> 1, hh = t & 1;
            for (int kk = 0; kk < 32; kk++) {
                const int k = hh * 32 + kk;
                dst[(size_t)n * D + half * 64 + k] = f2bf(lds[k * 129 + n]);
            }
        }
    } else if (b == 41) {
        // ---- sv = data_W @ score_W, s0 = data_b . score_W ----
        float* red = smem;
        if (t < D) {
            float acc = 0.f;
            for (int j = 0; j < D; j++) acc += dW[(size_t)t * D + j] * sWs[j];
            sv[t] = acc;
        }
        red[t] = (t < D) ? db[t] * sWs[t] : 0.f;
        __syncthreads();
        for (int s = 128; s > 0; s >>= 1) { if (t < s) red[t] += red[t + s]; __syncthreads(); }
        if (t == 0) s0[0] = red[0];
    } else {
        // ---- vec2bf grid-stride ----
        for (int i = (b - 42) * 256 + t; i < n4; i += (gridDim.x - 42) * 256) {
            const float4 v = ((const float4*)vecs)[i];
            uint2 o;
            o.x = (unsigned)f2bf(v.x) | ((unsigned)f2bf(v.y) << 16);
            o.y = (unsigned)f2bf(v.z) | ((unsigned)f2bf(v.w) << 16);
            ((uint2*)vbf)[i] = o;
        }
    }
}

// ============ merged leaf GEMM + embed (bf16 gather, W direct from global) ============
__global__ __launch_bounds__(256, 4) void leaf_embed_kernel(
    unsigned short* __restrict__ X,
    const unsigned short* __restrict__ vbf,
    const int* __restrict__ data,
    const int* __restrict__ perm,
    const int* __restrict__ gstart9,
    const int* __restrict__ glim8,
    const unsigned short* __restrict__ cwt,
    const float* __restrict__ dcomp,
    const float* __restrict__ sv, const float* __restrict__ s0p,
    const unsigned short* __restrict__ dwt,
    const float* __restrict__ db,
    float* __restrict__ out,
    int NI, int lbase_leaf)
{
    __shared__ unsigned short a_s[TS * LDSTR];   // ~34.8 KB
    const int t = threadIdx.x;
    const bool is_leaf = (blockIdx.x < LEAF_BLKS);
    const int r = t >> 1, h = t & 1;

    int e = 0, c;
    const unsigned short* Wg;
    const float* bias;
    if (is_leaf) {
        const int ts = blockIdx.x * TS;
        if (ts >= gstart9[8]) return;
        #pragma unroll
        for (int j = 1; j < 8; j++) if (ts >= gstart9[j]) e = j;
        const int p = ts + r;
        c = (p < glim8[e]) ? perm[lbase_leaf + p] : -1;
        Wg = cwt + (size_t)e * D * D;
        bias = dcomp + (size_t)e * D;
    } else {
        const int node = (blockIdx.x - LEAF_BLKS) * TS + r;
        c = (node < NI) ? node : -1;
        Wg = dwt;
        bias = db;
    }

    {   // stage A (bf16 gather) + fused leaf score
        unsigned short* dst = a_s + r * LDSTR + h * 64;
        if (c >= 0) {
            const uint4* src = (const uint4*)(vbf + (size_t)data[c] * D + h * 64);
            if (is_leaf) {
                float sc = 0.f;
                #pragma unroll
                for (int j = 0; j < 8; j++) {
                    const uint4 v = src[j];
                    const unsigned* pv = (const unsigned*)&v;
                    #pragma unroll
                    for (int u = 0; u < 4; u++) {
                        const int n = h * 64 + j * 8 + u * 2;
                        sc += bf2f((unsigned short)pv[u]) * sv[n]
                            + bf2f((unsigned short)(pv[u] >> 16)) * sv[n + 1];
                    }
                    ((uint4*)dst)[j] = v;
                }
                sc += __shfl_xor(sc, 1, 64);
                if (h == 0) out[c] = sc + s0p[0];
            } else {
                #pragma unroll
                for (int j = 0; j < 8; j++) ((uint4*)dst)[j] = src[j];
            }
        } else {
            #pragma unroll
            for (int j = 0; j < 8; j++) ((uint4*)dst)[j] = make_uint4(0u, 0u, 0u, 0u);
        }
    }
    __syncthreads();

    const int lane = t & 63, wv = t >> 6;
    const int cq = lane & 15, q = lane >> 4;
    const floatx4 z4 = {0.f, 0.f, 0.f, 0.f};
    floatx4 acc[8][2];
    #pragma unroll
    for (int i = 0; i < 8; i++) { acc[i][0] = z4; acc[i][1] = z4; }
    #pragma unroll
    for (int ks = 0; ks < 4; ks++) {
        shortx8 bfr[2];
        #pragma unroll
        for (int nl = 0; nl < 2; nl++) {
            const int n = (wv * 2 + nl) * 16 + cq;
            bfr[nl] = *(const shortx8*)(Wg + (size_t)n * D + ks * 32 + q * 8);
        }
        #pragma unroll
        for (int mt = 0; mt < 8; mt++) {
            const shortx8 af = *(const shortx8*)(a_s + (mt * 16 + cq) * LDSTR + ks * 32 + q * 8);
            acc[mt][0] = __builtin_amdgcn_mfma_f32_16x16x32_bf16(af, bfr[0], acc[mt][0], 0, 0, 0);
            acc[mt][1] = __builtin_amdgcn_mfma_f32_16x16x32_bf16(af, bfr[1], acc[mt][1], 0, 0, 0);
        }
    }
    __syncthreads();
    #pragma unroll
    for (int nl = 0; nl < 2; nl++) {
        const int n = (wv * 2 + nl) * 16 + cq;
        const float bn = bias[n];
        #pragma unroll
        for (int mt = 0; mt < 8; mt++) {
            #pragma unroll
            for (int rg = 0; rg < 4; rg++) {
                const int m = mt * 16 + q * 4 + rg;
                a_s[m * LDSTR + n] = f2bf(acc[mt][nl][rg] + bn);
            }
        }
    }
    __syncthreads();
    if (c >= 0) {
        uint4* dst = (uint4*)(X + (size_t)c * D + h * 64);
        const uint4* srcl = (const uint4*)(a_s + r * LDSTR + h * 64);
        #pragma unroll
        for (int j = 0; j < 8; j++) dst[j] = srcl[j];
    }
}

// ============ big tree GEMM (levels 15..13): combine+score+ReLU staged, W direct ============
__global__ __launch_bounds__(256, 4) void tree_gemm_kernel(
    unsigned short* __restrict__ X,
    const int* __restrict__ perm,
    const int* __restrict__ gstart9,
    const int* __restrict__ glim8,
    const unsigned short* __restrict__ ewt,
    const float* __restrict__ eb,
    const float* __restrict__ svec,
    float* __restrict__ out,
    int lbase)
{
    __shared__ unsigned short a_s[TS * LDSTR];
    const int t = threadIdx.x;
    const int ts = blockIdx.x * TS;
    if (ts >= gstart9[8]) return;
    int e = 0;
    #pragma unroll
    for (int j = 1; j < 8; j++) if (ts >= gstart9[j]) e = j;
    const int r = t >> 1, h = t & 1;
    const int p = ts + r;
    const int c = (p < glim8[e]) ? perm[lbase + p] : -1;
    const unsigned short* Wg = ewt + (size_t)e * D * D;

    {   // stage A: fused combine + score + ReLU
        unsigned short* dst = a_s + r * LDSTR + h * 64;
        if (c >= 0) {
            const uint4* xr = (const uint4*)(X + (size_t)c * D + h * 64);
            const uint4* ya = (const uint4*)(X + (size_t)(2 * c + 1) * D + h * 64);
            const uint4* yb = (const uint4*)(X + (size_t)(2 * c + 2) * D + h * 64);
            const float inv3 = 1.0f / 3.0f;
            float sc = 0.f;
            #pragma unroll
            for (int j = 0; j < 8; j++) {
                uint4 ra = xr[j], rb = ya[j], rc = yb[j];
                const unsigned* pa = (const unsigned*)&ra;
                const unsigned* pb = (const unsigned*)&rb;
                const unsigned* pc = (const unsigned*)&rc;
                unsigned ou[4];
                #pragma unroll
                for (int u = 0; u < 4; u++) {
                    const float h0 = (bf2f((unsigned short)pa[u]) + bf2f((unsigned short)pb[u])
                                    + bf2f((unsigned short)pc[u])) * inv3;
                    const float h1 = (bf2f((unsigned short)(pa[u] >> 16)) + bf2f((unsigned short)(pb[u] >> 16))
                                    + bf2f((unsigned short)(pc[u] >> 16))) * inv3;
                    const int n = h * 64 + j * 8 + u * 2;
                    sc += h0 * svec[n] + h1 * svec[n + 1];
                    unsigned short q0 = f2bf(h0), q1 = f2bf(h1);
                    q0 = (q0 & 0x8000u) ? 0 : q0;
                    q1 = (q1 & 0x8000u) ? 0 : q1;
                    ou[u] = (unsigned)q0 | ((unsigned)q1 << 16);
                }
                ((uint4*)dst)[j] = make_uint4(ou[0], ou[1], ou[2], ou[3]);
            }
            sc += __shfl_xor(sc, 1, 64);
            if (h == 0) out[c] = sc;
        } else {
            #pragma unroll
            for (int j = 0; j < 8; j++) ((uint4*)dst)[j] = make_uint4(0u, 0u, 0u, 0u);
        }
    }
    __syncthreads();
    const int lane = t & 63, wv = t >> 6;
    const int cq = lane & 15, q = lane >> 4;
    const floatx4 z4 = {0.f, 0.f, 0.f, 0.f};
    floatx4 acc[8][2];
    #pragma unroll
    for (int i = 0; i < 8; i++) { acc[i][0] = z4; acc[i][1] = z4; }
    #pragma unroll
    for (int ks = 0; ks < 4; ks++) {
        shortx8 bfr[2];
        #pragma unroll
        for (int nl = 0; nl < 2; nl++) {
            const int n = (wv * 2 + nl) * 16 + cq;
            bfr[nl] = *(const shortx8*)(Wg + (size_t)n * D + ks * 32 + q * 8);
        }
        #pragma unroll
        for (int mt = 0; mt < 8; mt++) {
            const shortx8 af = *(const shortx8*)(a_s + (mt * 16 + cq) * LDSTR + ks * 32 + q * 8);
            acc[mt][0] = __builtin_amdgcn_mfma_f32_16x16x32_bf16(af, bfr[0], acc[mt][0], 0, 0, 0);
            acc[mt][1] = __builtin_amdgcn_mfma_f32_16x16x32_bf16(af, bfr[1], acc[mt][1], 0, 0, 0);
        }
    }
    __syncthreads();
    #pragma unroll
    for (int nl = 0; nl < 2; nl++) {
        const int n = (wv * 2 + nl) * 16 + cq;
        const float bn = eb[(size_t)e * D + n];
        #pragma unroll
        for (int mt = 0; mt < 8; mt++) {
            #pragma unroll
            for (int rg = 0; rg < 4; rg++) {
                const int m = mt * 16 + q * 4 + rg;
                a_s[m * LDSTR + n] = f2bf(acc[mt][nl][rg] + bn);
            }
        }
    }
    __syncthreads();
    if (c >= 0) {
        uint4* dst = (uint4*)(X + (size_t)c * D + h * 64);
        const uint4* srcl = (const uint4*)(a_s + r * LDSTR + h * 64);
        #pragma unroll
        for (int j = 0; j < 8; j++) dst[j] = srcl[j];
    }
}

// ============ subtree kernel (top levels): block owns subtree, __syncthreads between depths ============
__global__ __launch_bounds__(256) void sub_kernel(
    unsigned short* __restrict__ X,
    const float* __restrict__ eW,
    const float* __restrict__ eb,
    const int* __restrict__ edges,
    const float* __restrict__ sW,
    float* __restrict__ out,
    int rbase, int nlev)
{
    __shared__ __align__(16) float xbuf[4][D];
    const int t = threadIdx.x, wv = t >> 6, lane = t & 63;
    const int u = rbase + blockIdx.x;
    const int j2 = lane * 2;
    const float inv3 = 1.0f / 3.0f;

    for (int lev = nlev - 1; lev >= 0; lev--) {
        const int first = ((u + 1) << lev) - 1;
        const int cnt = 1 << lev;
        for (int i = wv; i < cnt; i += 4) {
            const int n = first + i;
            const unsigned ra = *(const unsigned*)(X + (size_t)n * D + j2);
            const unsigned rb = *(const unsigned*)(X + (size_t)(2 * n + 1) * D + j2);
            const unsigned rc = *(const unsigned*)(X + (size_t)(2 * n + 2) * D + j2);
            const float h0 = (bf2f((unsigned short)ra) + bf2f((unsigned short)rb)
                            + bf2f((unsigned short)rc)) * inv3;
            const float h1 = (bf2f((unsigned short)(ra >> 16)) + bf2f((unsigned short)(rb >> 16))
                            + bf2f((unsigned short)(rc >> 16))) * inv3;
            float sc = h0 * sW[j2] + h1 * sW[j2 + 1];
            #pragma unroll
            for (int o = 32; o > 0; o >>= 1) sc += __shfl_xor(sc, o, 64);
            if (lane == 0) out[n] = sc;
            if (n == 0) continue;
            float2 x2 = make_float2(fmaxf(h0, 0.f), fmaxf(h1, 0.f));
            *(float2*)(xbuf[wv] + j2) = x2;
            const int e = edges[n];
            const float* W = eW + (size_t)e * D * D;
            float y0 = 0.f, y1 = 0.f;
            #pragma unroll 8
            for (int k4 = 0; k4 < 32; k4++) {
                const float4 xk = *(const float4*)(xbuf[wv] + k4 * 4);
                const float2 w0 = *(const float2*)(W + (size_t)(k4 * 4 + 0) * D + j2);
                const float2 w1 = *(const float2*)(W + (size_t)(k4 * 4 + 1) * D + j2);
                const float2 w2 = *(const float2*)(W + (size_t)(k4 * 4 + 2) * D + j2);
                const float2 w3 = *(const float2*)(W + (size_t)(k4 * 4 + 3) * D + j2);
                y0 += xk.x * w0.x + xk.y * w1.x + xk.z * w2.x + xk.w * w3.x;
                y1 += xk.x * w0.y + xk.y * w1.y + xk.z * w2.y + xk.w * w3.y;
            }
            y0 += eb[e * D + j2];
            y1 += eb[e * D + j2 + 1];
            const unsigned o = (unsigned)f2bf(y0) | ((unsigned)f2bf(y1) << 16);
            *(unsigned*)(X + (size_t)n * D + j2) = o;
        }
        __syncthreads();
    }
}

extern "C" void kernel_launch(void* const* d_in, const int* in_sizes, int n_in,
                              void* d_out, int out_size, void* d_ws, size_t ws_size,
                              hipStream_t stream) {
    const int*   data      = (const int*)d_in[0];
    const int*   edges     = (const int*)d_in[1];
    const float* data_vecs = (const float*)d_in[2];
    const float* data_W    = (const float*)d_in[3];
    const float* data_b    = (const float*)d_in[4];
    const float* edge_W    = (const float*)d_in[5];
    const float* edge_b    = (const float*)d_in[6];
    const float* score_W   = (const float*)d_in[7];
    float* out = (float*)d_out;

    const int Nn = in_sizes[0];          // 2^18 - 1
    const int NI = Nn >> 1;              // internal nodes: 2^17 - 1
    const int VD = in_sizes[2];          // V * D
    const int PERM_TOTAL = (Nn - 1) + LVLPAD * NLVL;

    char* w = (char*)d_ws;
    size_t off = 0;
    unsigned short* X = (unsigned short*)(w + off); off += (size_t)Nn * D * 2;
    int* perm = (int*)(w + off);  off += (size_t)PERM_TOTAL * 4;
    off = (off + 255) & ~(size_t)255;
    int* gstart  = (int*)(w + off); off += NLVL * 9 * 4;
    int* glim    = (int*)(w + off); off += NLVL * 8 * 4;
    int* gcnt128 = (int*)(w + off); off += 128 * 32 * 4;
    int* ctr     = (int*)(w + off); off += 32 * 4;
    off = (off + 255) & ~(size_t)255;
    float* dcomp = (float*)(w + off); off += 8 * D * 4;
    float* sv    = (float*)(w + off); off += D * 4;
    float* s0    = (float*)(w + off); off += 256;
    off = (off + 255) & ~(size_t)255;
    unsigned short* ewt = (unsigned short*)(w + off); off += (size_t)8 * D * D * 2;
    unsigned short* cwt = (unsigned short*)(w + off); off += (size_t)8 * D * D * 2;
    unsigned short* dwt = (unsigned short*)(w + off); off += (size_t)D * D * 2;
    off = (off + 255) & ~(size_t)255;
    unsigned short* vbf = (unsigned short*)(w + off); off += (size_t)VD * 2;

    // 1..3: sort (levels 13..16 only); no memsets needed anywhere
    count_kernel<<<128, 256, 0, stream>>>(edges, gcnt128, Nn);
    prefix_kernel<<<1, 256, 0, stream>>>(gcnt128, gstart, glim, ctr);
    const int place_blks = (Nn - 16383 + CHUNK - 1) / CHUNK;
    place_kernel<<<place_blks, 256, 0, stream>>>(edges, gstart, ctr, perm, Nn);

    // 4: fused prep (compose->cwt+dcomp, ewt/dwt transpose, sv/s0, vec2bf)
    prep_kernel<<<42 + 1024, 256, 0, stream>>>(
        data_W, data_b, edge_W, edge_b, score_W, data_vecs,
        ewt, cwt, dwt, dcomp, sv, s0, vbf, VD / 4);

    // 5: merged leaf GEMM (depth-17 leaves) + embed (internal raw), one launch
    {
        const int embed_blks = (NI + TS - 1) / TS;
        const int lbase_leaf = ((2 << 16) - 2) + LVLPAD * 16;
        leaf_embed_kernel<<<LEAF_BLKS + embed_blks, 256, 0, stream>>>(
            X, vbf, data, perm, gstart + 16 * 9, glim + 16 * 8,
            cwt, dcomp, sv, s0, dwt, data_b, out, NI, lbase_leaf);
    }

    // 6..8: big internal levels 15..13 (MFMA, edge-sorted tiles) -> depths 16..14
    for (int l = 15; l >= 13; l--) {
        const int M = 2 << l;
        const int lbase = ((2 << l) - 2) + LVLPAD * l;
        tree_gemm_kernel<<<M / TS + 8, 256, 0, stream>>>(
            X, perm, gstart + l * 9, glim + l * 8, ewt, edge_b, score_W, out, lbase);
    }

    // 9..12: top of tree via subtree-owned blocks (no grid barriers)
    sub_kernel<<<2048, 256, 0, stream>>>(X, edge_W, edge_b, edges, score_W, out, 2047, 3); // depths 13..11
    sub_kernel<<<128, 256, 0, stream>>>(X, edge_W, edge_b, edges, score_W, out, 127, 4);   // depths 10..7
    sub_kernel<<<8, 256, 0, stream>>>(X, edge_W, edge_b, edges, score_W, out, 7, 4);       // depths 6..3
    sub_kernel<<<1, 256, 0, stream>>>(X, edge_W, edge_b, edges, score_W, out, 0, 3);       // depths 2..0 + root
}